// Round 16
// baseline (342.872 us; speedup 1.0000x reference)
//
#include <hip/hip_runtime.h>
#include <hip/hip_bf16.h>

// Performer causal attention, chunked scan, MFMA bf16 everywhere.
// B=4 T=4096 H=12 E=64 M=266 (padded 288). mfma_f32_16x16x32_bf16.
// R12: stage_c wave-owns-row P2 (qa[9] loaded once); packed triangular Albuf.
// R13/R14: Vt overlaid on arena; launch_bounds(512,4) (no spills, ~56 VGPR).
// R15: feat_q phib -> [32][296] 4-phase store => 38.4KB LDS => 4 blocks/CU
//      (100% wave occupancy); stage_c k-stage uses all 512 threads.

typedef unsigned short u16;
typedef __attribute__((ext_vector_type(8))) short bf16x8;   // 8 bf16 = 4 VGPR
typedef __attribute__((ext_vector_type(4))) float f32x4;

constexpr int Tn = 4096, Hn = 12;
constexpr int MP = 288;       // padded feature dim
constexpr int Mn = 266;
constexpr int CH = 128;       // chunk length
constexpr int NC = 32;        // chunks
constexpr int BH = 48;

constexpr float DATA_NORM = 0.35355339059327379f;  // 64^-0.25
constexpr float SM_EPS = 1e-4f;
constexpr float N_EPS  = 1e-6f;
constexpr float RATIO  = 0.06131393152401153f;     // 266^-0.5

__device__ __forceinline__ u16 f2bf(float f) {
  __hip_bfloat16 h = __float2bfloat16(f);
  return __builtin_bit_cast(u16, h);
}
__device__ __forceinline__ float bf2f(u16 u) {
  return __uint_as_float(((unsigned)u) << 16);
}
__device__ __forceinline__ bf16x8 ldb(const u16* p) {
  return *reinterpret_cast<const bf16x8*>(p);
}
__device__ __forceinline__ f32x4 mfma16(bf16x8 a, bf16x8 b, f32x4 c) {
  return __builtin_amdgcn_mfma_f32_16x16x32_bf16(a, b, c, 0, 0, 0);
}
__device__ __forceinline__ void atomicMaxF(float* addr, float val) {
  if (val >= 0.f) atomicMax(reinterpret_cast<int*>(addr), __float_as_int(val));
  else atomicMin(reinterpret_cast<unsigned int*>(addr), __float_as_uint(val));
}
__device__ __forceinline__ void unpack8v(uint4 r, float* f) {
  f[0] = __uint_as_float(r.x << 16);
  f[1] = __uint_as_float(r.x & 0xffff0000u);
  f[2] = __uint_as_float(r.y << 16);
  f[3] = __uint_as_float(r.y & 0xffff0000u);
  f[4] = __uint_as_float(r.z << 16);
  f[5] = __uint_as_float(r.z & 0xffff0000u);
  f[6] = __uint_as_float(r.w << 16);
  f[7] = __uint_as_float(r.w & 0xffff0000u);
}
__device__ __forceinline__ uint4 pack8(const float* f) {
  uint4 r;
  r.x = (unsigned)f2bf(f[0]) | ((unsigned)f2bf(f[1]) << 16);
  r.y = (unsigned)f2bf(f[2]) | ((unsigned)f2bf(f[3]) << 16);
  r.z = (unsigned)f2bf(f[4]) | ((unsigned)f2bf(f[5]) << 16);
  r.w = (unsigned)f2bf(f[6]) | ((unsigned)f2bf(f[7]) << 16);
  return r;
}

// ---------------- prep: projbf [288][64] bf16 zero-padded; kmax init ----------------
__global__ void prep(const float* __restrict__ proj, u16* __restrict__ projbf,
                     float* __restrict__ kmax) {
  int idx = blockIdx.x * 256 + threadIdx.x;
  if (idx < MP * 64) {
    int m = idx >> 6, e = idx & 63;
    float v = (m < Mn) ? proj[m * 64 + e] : 0.f;
    projbf[idx] = f2bf(v);
  }
  if (blockIdx.x == 0 && threadIdx.x < BH) kmax[threadIdx.x] = -3.0e38f;
}

// ---------------- feat_q (R15): 512 thr, 128 rows, 4-phase [32][296] staging ----------------
__global__ __launch_bounds__(512, 4) void feat_q(
    const float* __restrict__ q, const u16* __restrict__ projbf,
    u16* __restrict__ phiq) {
  __shared__ __align__(16) u16 xt[128 * 72];     // 18,432
  __shared__ __align__(16) u16 phib[32 * 296];   // 18,944
  __shared__ float diag[128];
  const int tid = threadIdx.x;
  const int bh = blockIdx.x >> 5, tb = blockIdx.x & 31;
  const int b = bh / Hn, h = bh % Hn;
  const int t0 = tb * 128;
  {
    const int t = tid >> 2, e0 = (tid & 3) * 16;
    const float* row = q + (((size_t)b * Tn + t0 + t) * Hn + h) * 64 + e0;
    float ss = 0.f;
#pragma unroll
    for (int q4 = 0; q4 < 4; ++q4) {
      float4 vv = *reinterpret_cast<const float4*>(row + q4 * 4);
      float x0 = vv.x * DATA_NORM, x1 = vv.y * DATA_NORM;
      float x2 = vv.z * DATA_NORM, x3 = vv.w * DATA_NORM;
      ss += x0 * x0 + x1 * x1 + x2 * x2 + x3 * x3;
      ushort4 uu = make_ushort4(f2bf(x0), f2bf(x1), f2bf(x2), f2bf(x3));
      *reinterpret_cast<ushort4*>(&xt[t * 72 + e0 + q4 * 4]) = uu;
    }
    ss += __shfl_xor(ss, 1);
    ss += __shfl_xor(ss, 2);
    if ((tid & 3) == 0) diag[t] = 0.5f * ss;
  }
  __syncthreads();
  const int lane = tid & 63, wv = tid >> 6;
  const int lj = lane & 15, lg = lane >> 4;
  bf16x8 a0 = ldb(&xt[(wv * 16 + lj) * 72 + lg * 8]);
  bf16x8 a1 = ldb(&xt[(wv * 16 + lj) * 72 + 32 + lg * 8]);
  f32x4 acc[17];
#pragma unroll
  for (int mt = 0; mt < 17; ++mt) {
    const u16* br = &projbf[(mt * 16 + lj) * 64 + lg * 8];
    f32x4 z = {0.f, 0.f, 0.f, 0.f};
    z = mfma16(a0, ldb(br), z);
    z = mfma16(a1, ldb(br + 32), z);
    acc[mt] = z;
  }
  float rmax[4] = {-3e38f, -3e38f, -3e38f, -3e38f};
#pragma unroll
  for (int mt = 0; mt < 17; ++mt) {
    int m = mt * 16 + lj;
    if (m < Mn) {
#pragma unroll
      for (int r = 0; r < 4; ++r) rmax[r] = fmaxf(rmax[r], acc[mt][r]);
    }
  }
#pragma unroll
  for (int r = 0; r < 4; ++r) {
    rmax[r] = fmaxf(rmax[r], __shfl_xor(rmax[r], 1));
    rmax[r] = fmaxf(rmax[r], __shfl_xor(rmax[r], 2));
    rmax[r] = fmaxf(rmax[r], __shfl_xor(rmax[r], 4));
    rmax[r] = fmaxf(rmax[r], __shfl_xor(rmax[r], 8));
  }
  float dg[4];
#pragma unroll
  for (int r = 0; r < 4; ++r) dg[r] = diag[wv * 16 + lg * 4 + r];
#pragma unroll
  for (int mt = 0; mt < 17; ++mt) {
    int m = mt * 16 + lj;
#pragma unroll
    for (int r = 0; r < 4; ++r) {
      float val = 0.f;
      if (m < Mn)
        val = RATIO * (__expf(acc[mt][r] - dg[r] - rmax[r]) + SM_EPS);
      acc[mt][r] = val;
    }
  }
  const uint4 z4 = make_uint4(0, 0, 0, 0);
  for (int ph = 0; ph < 4; ++ph) {
    __syncthreads();   // phib free
    if ((wv >> 1) == ph) {
#pragma unroll
      for (int mt = 0; mt < 17; ++mt) {
#pragma unroll
        for (int r = 0; r < 4; ++r)
          phib[((wv & 1) * 16 + lg * 4 + r) * 296 + mt * 16 + lj] =
              f2bf(acc[mt][r]);
      }
    }
    __syncthreads();
    u16* ob2 = phiq + ((size_t)bh * Tn + t0 + ph * 32) * MP;
#pragma unroll
    for (int l = 0; l < 3; ++l) {
      int idx = tid + l * 512;
      if (idx < 1152) {
        int row = idx / 36, c8 = (idx % 36) * 8;
        uint4 o = (c8 >= 272) ? z4
                              : *reinterpret_cast<const uint4*>(&phib[row * 296 + c8]);
        *reinterpret_cast<uint4*>(&ob2[(size_t)row * MP + c8]) = o;
      }
    }
  }
}

// ---------------- feat_k (R9): 512 thr, 128 rows, global max only ----------------
__global__ __launch_bounds__(512) void feat_k(
    const float* __restrict__ k, const u16* __restrict__ projbf,
    float* __restrict__ kmax) {
  __shared__ __align__(16) u16 xt[128 * 72];
  __shared__ float wred[8];
  const int tid = threadIdx.x;
  const int bh = blockIdx.x >> 5, tb = blockIdx.x & 31;
  const int b = bh / Hn, h = bh % Hn;
  const int t0 = tb * 128;
  {
    const int t = tid >> 2, e0 = (tid & 3) * 16;
    const float* row = k + (((size_t)b * Tn + t0 + t) * Hn + h) * 64 + e0;
#pragma unroll
    for (int q4 = 0; q4 < 4; ++q4) {
      float4 vv = *reinterpret_cast<const float4*>(row + q4 * 4);
      ushort4 uu = make_ushort4(f2bf(vv.x * DATA_NORM), f2bf(vv.y * DATA_NORM),
                                f2bf(vv.z * DATA_NORM), f2bf(vv.w * DATA_NORM));
      *reinterpret_cast<ushort4*>(&xt[t * 72 + e0 + q4 * 4]) = uu;
    }
  }
  __syncthreads();
  const int lane = tid & 63, wv = tid >> 6;
  const int lj = lane & 15, lg = lane >> 4;
  bf16x8 a0 = ldb(&xt[(wv * 16 + lj) * 72 + lg * 8]);
  bf16x8 a1 = ldb(&xt[(wv * 16 + lj) * 72 + 32 + lg * 8]);
  float mx = -3e38f;
#pragma unroll
  for (int mt = 0; mt < 17; ++mt) {
    const u16* br = &projbf[(mt * 16 + lj) * 64 + lg * 8];
    f32x4 z = {0.f, 0.f, 0.f, 0.f};
    z = mfma16(a0, ldb(br), z);
    z = mfma16(a1, ldb(br + 32), z);
    int m = mt * 16 + lj;
    if (m < Mn)
      mx = fmaxf(mx, fmaxf(fmaxf(z[0], z[1]), fmaxf(z[2], z[3])));
  }
  mx = fmaxf(mx, __shfl_xor(mx, 1));
  mx = fmaxf(mx, __shfl_xor(mx, 2));
  mx = fmaxf(mx, __shfl_xor(mx, 4));
  mx = fmaxf(mx, __shfl_xor(mx, 8));
  mx = fmaxf(mx, __shfl_xor(mx, 16));
  mx = fmaxf(mx, __shfl_xor(mx, 32));
  if (lane == 0) wred[wv] = mx;
  __syncthreads();
  if (tid == 0) {
    float m2 = wred[0];
#pragma unroll
    for (int i = 1; i < 8; ++i) m2 = fmaxf(m2, wred[i]);
    atomicMaxF(&kmax[bh], m2);
  }
}

// ---------------- stage_a: KV^T partial + z partial; coalesced kvT write ----------------
__global__ __launch_bounds__(512) void stage_a(
    const float* __restrict__ v, const float* __restrict__ kk,
    const u16* __restrict__ projbf, const float* __restrict__ kmax,
    u16* __restrict__ kvT, float* __restrict__ zp) {
  __shared__ __align__(16) u16 knl[128 * 72];     // 18,432
  __shared__ __align__(16) u16 Vt[64 * 136];      // 17,408  (V^T [d][t])
  __shared__ __align__(16) u16 strip[288 * 40];   // 23,040  (phi_k^T, then kv staging)
  __shared__ float dkl[128];
  const int tid = threadIdx.x, lane = tid & 63, wv = tid >> 6;
  const int lj = lane & 15, lg = lane >> 4;
  const int c = blockIdx.x & 31, bh = blockIdx.x >> 5;
  const int b = bh / Hn, h = bh % Hn;
  const int t0 = c * CH;
  const float kmx = kmax[bh];

#pragma unroll
  for (int l = 0; l < 2; ++l) {
    int idx = tid + l * 512;
    int t = idx >> 3, e8 = (idx & 7) * 8;
    const float* kr = &kk[(((size_t)b * Tn + t0 + t) * Hn + h) * 64 + e8];
    float4 u0 = *reinterpret_cast<const float4*>(kr);
    float4 u1 = *reinterpret_cast<const float4*>(kr + 4);
    float x0 = u0.x * DATA_NORM, x1 = u0.y * DATA_NORM;
    float x2 = u0.z * DATA_NORM, x3 = u0.w * DATA_NORM;
    float x4 = u1.x * DATA_NORM, x5 = u1.y * DATA_NORM;
    float x6 = u1.z * DATA_NORM, x7 = u1.w * DATA_NORM;
    float ss = x0*x0 + x1*x1 + x2*x2 + x3*x3 + x4*x4 + x5*x5 + x6*x6 + x7*x7;
    *reinterpret_cast<ushort4*>(&knl[t * 72 + e8]) =
        make_ushort4(f2bf(x0), f2bf(x1), f2bf(x2), f2bf(x3));
    *reinterpret_cast<ushort4*>(&knl[t * 72 + e8 + 4]) =
        make_ushort4(f2bf(x4), f2bf(x5), f2bf(x6), f2bf(x7));
    ss += __shfl_xor(ss, 1);
    ss += __shfl_xor(ss, 2);
    ss += __shfl_xor(ss, 4);
    if ((tid & 7) == 0) dkl[t] = 0.5f * ss;
  }
#pragma unroll
  for (int l = 0; l < 4; ++l) {   // V -> V^T LDS bf16
    int idx = tid + l * 512;
    int t = idx >> 4, d4 = (idx & 15) * 4;
    float4 vv = *reinterpret_cast<const float4*>(
        &v[(((size_t)b * Tn + t0 + t) * Hn + h) * 64 + d4]);
    Vt[(d4 + 0) * 136 + t] = f2bf(vv.x);
    Vt[(d4 + 1) * 136 + t] = f2bf(vv.y);
    Vt[(d4 + 2) * 136 + t] = f2bf(vv.z);
    Vt[(d4 + 3) * 136 + t] = f2bf(vv.w);
  }

  float zacc = 0.f;
  f32x4 kvacc[9];
#pragma unroll
  for (int i = 0; i < 9; ++i) kvacc[i] = (f32x4){0.f, 0.f, 0.f, 0.f};
  const int dtile = wv & 3, mg = wv >> 2;
  __syncthreads();

  for (int s = 0; s < 4; ++s) {
    if (s) __syncthreads();
#pragma unroll
    for (int i = 0; i < 5; ++i) {
      int idx = wv + 8 * i;
      if (idx < 36) {
        int mt = idx % 18, th = idx / 18;
        const u16* ar = &projbf[(mt * 16 + lj) * 64 + lg * 8];
        int trow = s * 32 + th * 16 + lj;
        const u16* br = &knl[trow * 72 + lg * 8];
        f32x4 z = {0.f, 0.f, 0.f, 0.f};
        z = mfma16(ldb(ar), ldb(br), z);
        z = mfma16(ldb(ar + 32), ldb(br + 32), z);
        float dgk = dkl[trow];
#pragma unroll
        for (int r = 0; r < 4; ++r) {
          int m = mt * 16 + lg * 4 + r;
          float val = (m < Mn) ? RATIO * (__expf(z[r] - dgk - kmx) + SM_EPS) : 0.f;
          strip[m * 40 + th * 16 + lj] = f2bf(val);
        }
      }
    }
    __syncthreads();
    if (tid < MP) {
      const u16* srow = &strip[tid * 40];
#pragma unroll
      for (int o = 0; o < 32; o += 8) {
        bf16x8 vv = ldb(srow + o);
#pragma unroll
        for (int e = 0; e < 8; ++e) zacc += bf2f((u16)vv[e]);
      }
    }
    {
      bf16x8 av = ldb(&Vt[(dtile * 16 + lj) * 136 + s * 32 + lg * 8]);
#pragma unroll
      for (int i = 0; i < 9; ++i) {
        int mt = mg * 9 + i;
        kvacc[i] = mfma16(av, ldb(&strip[(mt * 16 + lj) * 40 + lg * 8]), kvacc[i]);
      }
    }
  }
  if (tid < MP) zp[((size_t)bh * NC + c) * MP + tid] = zacc;

  // coalesced kvT write via strip staging (two 32-row halves)
  const size_t base2 = ((size_t)(bh * NC + c) * 64) * MP;
  for (int half = 0; half < 2; ++half) {
    __syncthreads();
    if ((dtile >> 1) == half) {
#pragma unroll
      for (int i = 0; i < 9; ++i) {
        int mt = mg * 9 + i;
#pragma unroll
        for (int r = 0; r < 4; ++r)
          strip[((dtile & 1) * 16 + lg * 4 + r) * 296 + mt * 16 + lj] =
              f2bf(kvacc[i][r]);
      }
    }
    __syncthreads();
#pragma unroll
    for (int l = 0; l < 3; ++l) {
      int idx = tid + l * 512;
      if (idx < 1152) {
        int row = idx / 36, c8 = (idx % 36) * 8;
        *reinterpret_cast<uint4*>(&kvT[base2 + (size_t)(half * 32 + row) * MP + c8]) =
            *reinterpret_cast<const uint4*>(&strip[row * 296 + c8]);
      }
    }
  }
}

// ---------------- exclusive prefix scans over chunks (uint4 vectorized) ----------------
__global__ void scan_kv(u16* __restrict__ kvT) {
  int idx = blockIdx.x * 256 + threadIdx.x;          // 48*64*36
  if (idx >= BH * 64 * 36) return;
  int m8 = (idx % 36) * 8;
  int r = idx / 36;
  int d = r & 63, bh = r >> 6;
  u16* p = kvT + ((size_t)(bh * NC) * 64 + d) * MP + m8;
  const size_t cs = (size_t)64 * MP;
  float acc[8];
#pragma unroll
  for (int qq = 0; qq < 8; ++qq) acc[qq] = 0.f;
  for (int c = 0; c < NC; ++c) {
    uint4 raw = *reinterpret_cast<const uint4*>(p + c * cs);
    float in[8];
    unpack8v(raw, in);
    *reinterpret_cast<uint4*>(p + c * cs) = pack8(acc);
#pragma unroll
    for (int qq = 0; qq < 8; ++qq) acc[qq] += in[qq];
  }
}

__global__ void scan_z(float* __restrict__ zp) {
  int idx = blockIdx.x * 256 + threadIdx.x;          // 48*288
  if (idx >= BH * MP) return;
  int m = idx % MP, bh = idx / MP;
  float* p = zp + (size_t)bh * NC * MP + m;
  float acc = 0.f;
  for (int c = 0; c < NC; ++c) {
    float x = p[(size_t)c * MP];
    p[(size_t)c * MP] = acc;
    acc += x;
  }
}

// ---------------- stage_c (R15): R14 + full-width k-stage ----------------
// A = mask(QK^T) with phi_k recomputed per 32-row quarter; out = (A@V + Q@S_prev)/den
// Albuf packed triangular: tile-row tb rows have length 16(tb+1). 18KB.
// arena: quarters = phik_q[32][296] + knq[32][72]; after quarter loop = Vt[64][136].
__global__ __launch_bounds__(512, 4) void stage_c(
    const float* __restrict__ v, const float* __restrict__ kk,
    const u16* __restrict__ projbf, const float* __restrict__ kmax,
    const u16* __restrict__ phiq, const u16* __restrict__ kvT,
    const float* __restrict__ zp, float* __restrict__ out) {
  __shared__ __align__(16) u16 Albuf[9216];        // 18,432 (packed triangular)
  __shared__ __align__(16) u16 arena[11776];       // 23,552
  __shared__ float zl[MP];
  __shared__ float dklq[32];
  __shared__ float qzb[128];
  __shared__ float den[128];

  u16* phik_q = arena;              // [32][296]
  u16* knq    = arena + 32 * 296;   // [32][72]

  const int tid = threadIdx.x, lane = tid & 63, wv = tid >> 6;
  const int lj = lane & 15, lg = lane >> 4;
  const int c = blockIdx.x & 31, bh = blockIdx.x >> 5;
  const int b = bh / Hn, h = bh % Hn;
  const int t0 = c * CH;
  const float kmx = kmax[bh];
  const size_t qbase = ((size_t)bh * Tn + t0) * MP;
  const size_t kvbase = ((size_t)(bh * NC + c) * 64) * MP;

  // top prefetch: qa = phi_q A-fragments for row-tile wv (used by P2 AND P4)
  bf16x8 qa[9];
#pragma unroll
  for (int ks = 0; ks < 9; ++ks)
    qa[ks] = ldb(&phiq[qbase + (size_t)(wv * 16 + lj) * MP + ks * 32 + lg * 8]);
  __builtin_amdgcn_sched_barrier(0);

  if (tid < MP) zl[tid] = zp[((size_t)bh * NC + c) * MP + tid];

  for (int qq = 0; qq < 4; ++qq) {
    // stage raw k quarter (32 rows) -> knq bf16 + dklq; all 512 threads
    {
      int t = tid >> 4, e4 = (tid & 15) * 4;
      const float* kr = &kk[(((size_t)b * Tn + t0 + qq * 32 + t) * Hn + h) * 64 + e4];
      float4 u0 = *reinterpret_cast<const float4*>(kr);
      float x0 = u0.x * DATA_NORM, x1 = u0.y * DATA_NORM;
      float x2 = u0.z * DATA_NORM, x3 = u0.w * DATA_NORM;
      float ss = x0*x0 + x1*x1 + x2*x2 + x3*x3;
      *reinterpret_cast<ushort4*>(&knq[t * 72 + e4]) =
          make_ushort4(f2bf(x0), f2bf(x1), f2bf(x2), f2bf(x3));
      ss += __shfl_xor(ss, 1);
      ss += __shfl_xor(ss, 2);
      ss += __shfl_xor(ss, 4);
      ss += __shfl_xor(ss, 8);
      if ((tid & 15) == 0) dklq[t] = 0.5f * ss;
    }
    __syncthreads();   // knq ready (covers zl on first iteration)

    // P1: phi_k for quarter -> phik_q [32][296]; 36 units (2 t-tiles x 18 m-tiles)
    for (int u = wv; u < 36; u += 8) {
      int t2 = u / 18, mt = u % 18;
      bf16x8 a0 = ldb(&knq[(t2 * 16 + lj) * 72 + lg * 8]);
      bf16x8 a1 = ldb(&knq[(t2 * 16 + lj) * 72 + 32 + lg * 8]);
      const u16* br = &projbf[(mt * 16 + lj) * 64 + lg * 8];
      f32x4 z = {0.f, 0.f, 0.f, 0.f};
      z = mfma16(a0, ldb(br), z);
      z = mfma16(a1, ldb(br + 32), z);
      int m = mt * 16 + lj;
      int tq = t2 * 16 + lg * 4;
#pragma unroll
      for (int r = 0; r < 4; ++r) {
        float val = (m < Mn)
            ? RATIO * (__expf(z[r] - dklq[tq + r] - kmx) + SM_EPS) : 0.f;
        phik_q[(tq + r) * 296 + m] = f2bf(val);
      }
    }
    __syncthreads();   // phik_q ready

    // P2: wave-owns-row. Wave wv computes tiles (wv, tp) for tp in this quarter.
    const int tp0 = 2 * qq, tp1 = 2 * qq + 1;
    const bool ha = (tp0 <= wv), hb = (tp1 <= wv);
    if (ha) {
      f32x4 accA = {0.f, 0.f, 0.f, 0.f}, accB = {0.f, 0.f, 0.f, 0.f};
      __builtin_amdgcn_s_setprio(1);
#pragma unroll
      for (int ks = 0; ks < 9; ++ks) {
        int m0 = ks * 32;
        accA = mfma16(qa[ks], ldb(&phik_q[lj * 296 + m0 + lg * 8]), accA);
        if (hb)
          accB = mfma16(qa[ks], ldb(&phik_q[(16 + lj) * 296 + m0 + lg * 8]), accB);
      }
      __builtin_amdgcn_s_setprio(0);
      const int rb = 128 * wv * (wv + 1);
      const int pitch = 16 * (wv + 1);
#pragma unroll
      for (int pick = 0; pick < 2; ++pick) {
        if (pick == 1 && !hb) break;
        int tp = pick ? tp1 : tp0;
        f32x4 a = pick ? accB : accA;
        if (tp == wv) {   // diagonal tile mask
#pragma unroll
          for (int r = 0; r < 4; ++r)
            if (lj > lg * 4 + r) a[r] = 0.f;
        }
#pragma unroll
        for (int r = 0; r < 4; ++r)
          Albuf[rb + (lg * 4 + r) * pitch + tp * 16 + lj] = f2bf(a[r]);
      }
    }
    __syncthreads();   // Albuf quarter-columns done; arena free for next quarter
  }

  // stage V^T into arena (phik_q/knq dead)
  u16* Vt = arena;
#pragma unroll
  for (int l = 0; l < 4; ++l) {
    int idx = tid + l * 512;
    int t = idx >> 4, d4 = (idx & 15) * 4;
    float4 vv = *reinterpret_cast<const float4*>(
        &v[(((size_t)b * Tn + t0 + t) * Hn + h) * 64 + d4]);
    Vt[(d4 + 0) * 136 + t] = f2bf(vv.x);
    Vt[(d4 + 1) * 136 + t] = f2bf(vv.y);
    Vt[(d4 + 2) * 136 + t] = f2bf(vv.z);
    Vt[(d4 + 3) * 136 + t] = f2bf(vv.w);
  }

  // prefetch P4 first kvT quad; pin issue before the barrier
  bf16x8 kbA[4], kbB[4];
#pragma unroll
  for (int dt = 0; dt < 4; ++dt)
    kbA[dt] = ldb(&kvT[kvbase + (size_t)(dt * 16 + lj) * MP + lg * 8]);
  __builtin_amdgcn_sched_barrier(0);
  __syncthreads();   // Vt ready

  // P3: O += A @ V (triangular k-step skip, packed A rows)
  f32x4 oacc[4];
#pragma unroll
  for (int dt = 0; dt < 4; ++dt) oacc[dt] = (f32x4){0.f, 0.f, 0.f, 0.f};
  const int ksteps = (wv >> 1) + 1;
  const int rowA = 128 * wv * (wv + 1) + lj * 16 * (wv + 1);
  const bf16x8 zf = {0, 0, 0, 0, 0, 0, 0, 0};
  __builtin_amdgcn_s_setprio(1);
  for (int ks = 0; ks < ksteps; ++ks) {
    bool dead = ((wv & 1) == 0) && (ks == ksteps - 1) && (lg >= 2);
    bf16x8 af = dead ? zf : ldb(&Albuf[rowA + ks * 32 + lg * 8]);
#pragma unroll
    for (int dt = 0; dt < 4; ++dt) {
      bf16x8 bf = ldb(&Vt[(dt * 16 + lj) * 136 + ks * 32 + lg * 8]);
      oacc[dt] = mfma16(af, bf, oacc[dt]);
    }
  }
  __builtin_amdgcn_s_setprio(0);

  // P4: O += phi_q @ S_prev; B double-buffered in regs; fused qz
  float qz = 0.f;
#pragma unroll
  for (int ks = 0; ks < 9; ++ks) {
    const bf16x8* cur = (ks & 1) ? kbB : kbA;
    bf16x8* nxt = (ks & 1) ? kbA : kbB;
    if (ks < 8) {
      int m1 = (ks + 1) * 32;
#pragma unroll
      for (int dt = 0; dt < 4; ++dt)
        nxt[dt] = ldb(&kvT[kvbase + (size_t)(dt * 16 + lj) * MP + m1 + lg * 8]);
    }
#pragma unroll
    for (int e = 0; e < 8; ++e)
      qz += bf2f((u16)qa[ks][e]) * zl[ks * 32 + lg * 8 + e];
#pragma unroll
    for (int dt = 0; dt < 4; ++dt)
      oacc[dt] = mfma16(qa[ks], cur[dt], oacc[dt]);
  }
  qz += __shfl_xor(qz, 16);
  qz += __shfl_xor(qz, 32);
  if (lane < 16) qzb[wv * 16 + lane] = qz;
  __syncthreads();

  // den from packed bf16 A rows (R7-validated) + qz + eps
  if (tid < 128) {
    int tb2 = tid >> 4;
    int Lr = 16 * (tb2 + 1);
    const u16* arow = &Albuf[128 * tb2 * (tb2 + 1) + (tid & 15) * Lr];
    float s = qzb[tid] + N_EPS;
    for (int cc = 0; cc < Lr; cc += 8) {
      bf16x8 vv = ldb(arow + cc);
#pragma unroll
      for (int e = 0; e < 8; ++e) s += bf2f((u16)vv[e]);
    }
    den[tid] = s;
  }
  __syncthreads();

#pragma unroll
  for (int dt = 0; dt < 4; ++dt) {
#pragma unroll
    for (int r = 0; r < 4; ++r) {
      int tl = wv * 16 + lg * 4 + r;
      float o = oacc[dt][r] / den[tl];
      out[(((size_t)b * Tn + t0 + tl) * Hn + h) * 64 + dt * 16 + lj] = o;
    }
  }
}

extern "C" void kernel_launch(void* const* d_in, const int* in_sizes, int n_in,
                              void* d_out, int out_size, void* d_ws, size_t ws_size,
                              hipStream_t stream) {
  const float* q = (const float*)d_in[0];
  const float* k = (const float*)d_in[1];
  const float* v = (const float*)d_in[2];
  const float* proj = (const float*)d_in[3];
  float* out = (float*)d_out;

  char* ws = (char*)d_ws;
  const size_t phiq_b = (size_t)BH * Tn * MP * 2;        // 113,246,208
  const size_t kvT_b  = (size_t)BH * NC * 64 * MP * 2;   //  56,623,104
  const size_t zp_b   = (size_t)BH * NC * MP * 4;        //   1,769,472
  const size_t pj_b   = (size_t)MP * 64 * 2;             //      36,864

  size_t off = 0;
  u16*   phiq  = (u16*)(ws + off);  off += phiq_b;
  u16*   kvT   = (u16*)(ws + off);  off += kvT_b;
  float* zp    = (float*)(ws + off); off += zp_b;
  u16*   projbf= (u16*)(ws + off);  off += pj_b;
  float* kmax  = (float*)(ws + off);

  prep<<<72, 256, 0, stream>>>(proj, projbf, kmax);
  feat_k<<<BH * 32, 512, 0, stream>>>(k, projbf, kmax);
  feat_q<<<BH * 32, 512, 0, stream>>>(q, projbf, phiq);
  stage_a<<<BH * NC, 512, 0, stream>>>(v, k, projbf, kmax, kvT, zp);
  scan_kv<<<(BH * 64 * 36 + 255) / 256, 256, 0, stream>>>(kvT);
  scan_z<<<(BH * MP + 255) / 256, 256, 0, stream>>>(zp);
  stage_c<<<BH * NC, 512, 0, stream>>>(v, k, projbf, kmax, phiq, kvT, zp, out);
}

// Round 17
// 342.217 us; speedup vs baseline: 1.0019x; 1.0019x over previous
//
#include <hip/hip_runtime.h>
#include <hip/hip_bf16.h>

// Performer causal attention, chunked scan, MFMA bf16 everywhere.
// B=4 T=4096 H=12 E=64 M=266 (padded 288). mfma_f32_16x16x32_bf16.
// R12: stage_c wave-owns-row P2 (qa[9] loaded once); packed triangular Albuf.
// R13/R14: Vt overlaid on arena; launch_bounds(512,4).
// R15: feat_q 4-phase staging (38.4KB LDS); stage_c full-width k-stage.
// R16: stage_c Albuf rows padded +8 u16 (pitch never 0 mod 32 dwords -> kills
//      the 8.2M LDS bank conflicts); k prefetched to regs one quarter ahead.

typedef unsigned short u16;
typedef __attribute__((ext_vector_type(8))) short bf16x8;   // 8 bf16 = 4 VGPR
typedef __attribute__((ext_vector_type(4))) float f32x4;

constexpr int Tn = 4096, Hn = 12;
constexpr int MP = 288;       // padded feature dim
constexpr int Mn = 266;
constexpr int CH = 128;       // chunk length
constexpr int NC = 32;        // chunks
constexpr int BH = 48;

constexpr float DATA_NORM = 0.35355339059327379f;  // 64^-0.25
constexpr float SM_EPS = 1e-4f;
constexpr float N_EPS  = 1e-6f;
constexpr float RATIO  = 0.06131393152401153f;     // 266^-0.5

__device__ __forceinline__ u16 f2bf(float f) {
  __hip_bfloat16 h = __float2bfloat16(f);
  return __builtin_bit_cast(u16, h);
}
__device__ __forceinline__ float bf2f(u16 u) {
  return __uint_as_float(((unsigned)u) << 16);
}
__device__ __forceinline__ bf16x8 ldb(const u16* p) {
  return *reinterpret_cast<const bf16x8*>(p);
}
__device__ __forceinline__ f32x4 mfma16(bf16x8 a, bf16x8 b, f32x4 c) {
  return __builtin_amdgcn_mfma_f32_16x16x32_bf16(a, b, c, 0, 0, 0);
}
__device__ __forceinline__ void atomicMaxF(float* addr, float val) {
  if (val >= 0.f) atomicMax(reinterpret_cast<int*>(addr), __float_as_int(val));
  else atomicMin(reinterpret_cast<unsigned int*>(addr), __float_as_uint(val));
}
__device__ __forceinline__ void unpack8v(uint4 r, float* f) {
  f[0] = __uint_as_float(r.x << 16);
  f[1] = __uint_as_float(r.x & 0xffff0000u);
  f[2] = __uint_as_float(r.y << 16);
  f[3] = __uint_as_float(r.y & 0xffff0000u);
  f[4] = __uint_as_float(r.z << 16);
  f[5] = __uint_as_float(r.z & 0xffff0000u);
  f[6] = __uint_as_float(r.w << 16);
  f[7] = __uint_as_float(r.w & 0xffff0000u);
}
__device__ __forceinline__ uint4 pack8(const float* f) {
  uint4 r;
  r.x = (unsigned)f2bf(f[0]) | ((unsigned)f2bf(f[1]) << 16);
  r.y = (unsigned)f2bf(f[2]) | ((unsigned)f2bf(f[3]) << 16);
  r.z = (unsigned)f2bf(f[4]) | ((unsigned)f2bf(f[5]) << 16);
  r.w = (unsigned)f2bf(f[6]) | ((unsigned)f2bf(f[7]) << 16);
  return r;
}

// ---------------- prep: projbf [288][64] bf16 zero-padded; kmax init ----------------
__global__ void prep(const float* __restrict__ proj, u16* __restrict__ projbf,
                     float* __restrict__ kmax) {
  int idx = blockIdx.x * 256 + threadIdx.x;
  if (idx < MP * 64) {
    int m = idx >> 6, e = idx & 63;
    float v = (m < Mn) ? proj[m * 64 + e] : 0.f;
    projbf[idx] = f2bf(v);
  }
  if (blockIdx.x == 0 && threadIdx.x < BH) kmax[threadIdx.x] = -3.0e38f;
}

// ---------------- feat_q (R15): 512 thr, 128 rows, 4-phase [32][296] staging ----------------
__global__ __launch_bounds__(512, 4) void feat_q(
    const float* __restrict__ q, const u16* __restrict__ projbf,
    u16* __restrict__ phiq) {
  __shared__ __align__(16) u16 xt[128 * 72];     // 18,432
  __shared__ __align__(16) u16 phib[32 * 296];   // 18,944
  __shared__ float diag[128];
  const int tid = threadIdx.x;
  const int bh = blockIdx.x >> 5, tb = blockIdx.x & 31;
  const int b = bh / Hn, h = bh % Hn;
  const int t0 = tb * 128;
  {
    const int t = tid >> 2, e0 = (tid & 3) * 16;
    const float* row = q + (((size_t)b * Tn + t0 + t) * Hn + h) * 64 + e0;
    float ss = 0.f;
#pragma unroll
    for (int q4 = 0; q4 < 4; ++q4) {
      float4 vv = *reinterpret_cast<const float4*>(row + q4 * 4);
      float x0 = vv.x * DATA_NORM, x1 = vv.y * DATA_NORM;
      float x2 = vv.z * DATA_NORM, x3 = vv.w * DATA_NORM;
      ss += x0 * x0 + x1 * x1 + x2 * x2 + x3 * x3;
      ushort4 uu = make_ushort4(f2bf(x0), f2bf(x1), f2bf(x2), f2bf(x3));
      *reinterpret_cast<ushort4*>(&xt[t * 72 + e0 + q4 * 4]) = uu;
    }
    ss += __shfl_xor(ss, 1);
    ss += __shfl_xor(ss, 2);
    if ((tid & 3) == 0) diag[t] = 0.5f * ss;
  }
  __syncthreads();
  const int lane = tid & 63, wv = tid >> 6;
  const int lj = lane & 15, lg = lane >> 4;
  bf16x8 a0 = ldb(&xt[(wv * 16 + lj) * 72 + lg * 8]);
  bf16x8 a1 = ldb(&xt[(wv * 16 + lj) * 72 + 32 + lg * 8]);
  f32x4 acc[17];
#pragma unroll
  for (int mt = 0; mt < 17; ++mt) {
    const u16* br = &projbf[(mt * 16 + lj) * 64 + lg * 8];
    f32x4 z = {0.f, 0.f, 0.f, 0.f};
    z = mfma16(a0, ldb(br), z);
    z = mfma16(a1, ldb(br + 32), z);
    acc[mt] = z;
  }
  float rmax[4] = {-3e38f, -3e38f, -3e38f, -3e38f};
#pragma unroll
  for (int mt = 0; mt < 17; ++mt) {
    int m = mt * 16 + lj;
    if (m < Mn) {
#pragma unroll
      for (int r = 0; r < 4; ++r) rmax[r] = fmaxf(rmax[r], acc[mt][r]);
    }
  }
#pragma unroll
  for (int r = 0; r < 4; ++r) {
    rmax[r] = fmaxf(rmax[r], __shfl_xor(rmax[r], 1));
    rmax[r] = fmaxf(rmax[r], __shfl_xor(rmax[r], 2));
    rmax[r] = fmaxf(rmax[r], __shfl_xor(rmax[r], 4));
    rmax[r] = fmaxf(rmax[r], __shfl_xor(rmax[r], 8));
  }
  float dg[4];
#pragma unroll
  for (int r = 0; r < 4; ++r) dg[r] = diag[wv * 16 + lg * 4 + r];
#pragma unroll
  for (int mt = 0; mt < 17; ++mt) {
    int m = mt * 16 + lj;
#pragma unroll
    for (int r = 0; r < 4; ++r) {
      float val = 0.f;
      if (m < Mn)
        val = RATIO * (__expf(acc[mt][r] - dg[r] - rmax[r]) + SM_EPS);
      acc[mt][r] = val;
    }
  }
  const uint4 z4 = make_uint4(0, 0, 0, 0);
  for (int ph = 0; ph < 4; ++ph) {
    __syncthreads();   // phib free
    if ((wv >> 1) == ph) {
#pragma unroll
      for (int mt = 0; mt < 17; ++mt) {
#pragma unroll
        for (int r = 0; r < 4; ++r)
          phib[((wv & 1) * 16 + lg * 4 + r) * 296 + mt * 16 + lj] =
              f2bf(acc[mt][r]);
      }
    }
    __syncthreads();
    u16* ob2 = phiq + ((size_t)bh * Tn + t0 + ph * 32) * MP;
#pragma unroll
    for (int l = 0; l < 3; ++l) {
      int idx = tid + l * 512;
      if (idx < 1152) {
        int row = idx / 36, c8 = (idx % 36) * 8;
        uint4 o = (c8 >= 272) ? z4
                              : *reinterpret_cast<const uint4*>(&phib[row * 296 + c8]);
        *reinterpret_cast<uint4*>(&ob2[(size_t)row * MP + c8]) = o;
      }
    }
  }
}

// ---------------- feat_k (R9): 512 thr, 128 rows, global max only ----------------
__global__ __launch_bounds__(512) void feat_k(
    const float* __restrict__ k, const u16* __restrict__ projbf,
    float* __restrict__ kmax) {
  __shared__ __align__(16) u16 xt[128 * 72];
  __shared__ float wred[8];
  const int tid = threadIdx.x;
  const int bh = blockIdx.x >> 5, tb = blockIdx.x & 31;
  const int b = bh / Hn, h = bh % Hn;
  const int t0 = tb * 128;
  {
    const int t = tid >> 2, e0 = (tid & 3) * 16;
    const float* row = k + (((size_t)b * Tn + t0 + t) * Hn + h) * 64 + e0;
#pragma unroll
    for (int q4 = 0; q4 < 4; ++q4) {
      float4 vv = *reinterpret_cast<const float4*>(row + q4 * 4);
      ushort4 uu = make_ushort4(f2bf(vv.x * DATA_NORM), f2bf(vv.y * DATA_NORM),
                                f2bf(vv.z * DATA_NORM), f2bf(vv.w * DATA_NORM));
      *reinterpret_cast<ushort4*>(&xt[t * 72 + e0 + q4 * 4]) = uu;
    }
  }
  __syncthreads();
  const int lane = tid & 63, wv = tid >> 6;
  const int lj = lane & 15, lg = lane >> 4;
  bf16x8 a0 = ldb(&xt[(wv * 16 + lj) * 72 + lg * 8]);
  bf16x8 a1 = ldb(&xt[(wv * 16 + lj) * 72 + 32 + lg * 8]);
  float mx = -3e38f;
#pragma unroll
  for (int mt = 0; mt < 17; ++mt) {
    const u16* br = &projbf[(mt * 16 + lj) * 64 + lg * 8];
    f32x4 z = {0.f, 0.f, 0.f, 0.f};
    z = mfma16(a0, ldb(br), z);
    z = mfma16(a1, ldb(br + 32), z);
    int m = mt * 16 + lj;
    if (m < Mn)
      mx = fmaxf(mx, fmaxf(fmaxf(z[0], z[1]), fmaxf(z[2], z[3])));
  }
  mx = fmaxf(mx, __shfl_xor(mx, 1));
  mx = fmaxf(mx, __shfl_xor(mx, 2));
  mx = fmaxf(mx, __shfl_xor(mx, 4));
  mx = fmaxf(mx, __shfl_xor(mx, 8));
  mx = fmaxf(mx, __shfl_xor(mx, 16));
  mx = fmaxf(mx, __shfl_xor(mx, 32));
  if (lane == 0) wred[wv] = mx;
  __syncthreads();
  if (tid == 0) {
    float m2 = wred[0];
#pragma unroll
    for (int i = 1; i < 8; ++i) m2 = fmaxf(m2, wred[i]);
    atomicMaxF(&kmax[bh], m2);
  }
}

// ---------------- stage_a: KV^T partial + z partial; coalesced kvT write ----------------
__global__ __launch_bounds__(512) void stage_a(
    const float* __restrict__ v, const float* __restrict__ kk,
    const u16* __restrict__ projbf, const float* __restrict__ kmax,
    u16* __restrict__ kvT, float* __restrict__ zp) {
  __shared__ __align__(16) u16 knl[128 * 72];     // 18,432
  __shared__ __align__(16) u16 Vt[64 * 136];      // 17,408  (V^T [d][t])
  __shared__ __align__(16) u16 strip[288 * 40];   // 23,040  (phi_k^T, then kv staging)
  __shared__ float dkl[128];
  const int tid = threadIdx.x, lane = tid & 63, wv = tid >> 6;
  const int lj = lane & 15, lg = lane >> 4;
  const int c = blockIdx.x & 31, bh = blockIdx.x >> 5;
  const int b = bh / Hn, h = bh % Hn;
  const int t0 = c * CH;
  const float kmx = kmax[bh];

#pragma unroll
  for (int l = 0; l < 2; ++l) {
    int idx = tid + l * 512;
    int t = idx >> 3, e8 = (idx & 7) * 8;
    const float* kr = &kk[(((size_t)b * Tn + t0 + t) * Hn + h) * 64 + e8];
    float4 u0 = *reinterpret_cast<const float4*>(kr);
    float4 u1 = *reinterpret_cast<const float4*>(kr + 4);
    float x0 = u0.x * DATA_NORM, x1 = u0.y * DATA_NORM;
    float x2 = u0.z * DATA_NORM, x3 = u0.w * DATA_NORM;
    float x4 = u1.x * DATA_NORM, x5 = u1.y * DATA_NORM;
    float x6 = u1.z * DATA_NORM, x7 = u1.w * DATA_NORM;
    float ss = x0*x0 + x1*x1 + x2*x2 + x3*x3 + x4*x4 + x5*x5 + x6*x6 + x7*x7;
    *reinterpret_cast<ushort4*>(&knl[t * 72 + e8]) =
        make_ushort4(f2bf(x0), f2bf(x1), f2bf(x2), f2bf(x3));
    *reinterpret_cast<ushort4*>(&knl[t * 72 + e8 + 4]) =
        make_ushort4(f2bf(x4), f2bf(x5), f2bf(x6), f2bf(x7));
    ss += __shfl_xor(ss, 1);
    ss += __shfl_xor(ss, 2);
    ss += __shfl_xor(ss, 4);
    if ((tid & 7) == 0) dkl[t] = 0.5f * ss;
  }
#pragma unroll
  for (int l = 0; l < 4; ++l) {   // V -> V^T LDS bf16
    int idx = tid + l * 512;
    int t = idx >> 4, d4 = (idx & 15) * 4;
    float4 vv = *reinterpret_cast<const float4*>(
        &v[(((size_t)b * Tn + t0 + t) * Hn + h) * 64 + d4]);
    Vt[(d4 + 0) * 136 + t] = f2bf(vv.x);
    Vt[(d4 + 1) * 136 + t] = f2bf(vv.y);
    Vt[(d4 + 2) * 136 + t] = f2bf(vv.z);
    Vt[(d4 + 3) * 136 + t] = f2bf(vv.w);
  }

  float zacc = 0.f;
  f32x4 kvacc[9];
#pragma unroll
  for (int i = 0; i < 9; ++i) kvacc[i] = (f32x4){0.f, 0.f, 0.f, 0.f};
  const int dtile = wv & 3, mg = wv >> 2;
  __syncthreads();

  for (int s = 0; s < 4; ++s) {
    if (s) __syncthreads();
#pragma unroll
    for (int i = 0; i < 5; ++i) {
      int idx = wv + 8 * i;
      if (idx < 36) {
        int mt = idx % 18, th = idx / 18;
        const u16* ar = &projbf[(mt * 16 + lj) * 64 + lg * 8];
        int trow = s * 32 + th * 16 + lj;
        const u16* br = &knl[trow * 72 + lg * 8];
        f32x4 z = {0.f, 0.f, 0.f, 0.f};
        z = mfma16(ldb(ar), ldb(br), z);
        z = mfma16(ldb(ar + 32), ldb(br + 32), z);
        float dgk = dkl[trow];
#pragma unroll
        for (int r = 0; r < 4; ++r) {
          int m = mt * 16 + lg * 4 + r;
          float val = (m < Mn) ? RATIO * (__expf(z[r] - dgk - kmx) + SM_EPS) : 0.f;
          strip[m * 40 + th * 16 + lj] = f2bf(val);
        }
      }
    }
    __syncthreads();
    if (tid < MP) {
      const u16* srow = &strip[tid * 40];
#pragma unroll
      for (int o = 0; o < 32; o += 8) {
        bf16x8 vv = ldb(srow + o);
#pragma unroll
        for (int e = 0; e < 8; ++e) zacc += bf2f((u16)vv[e]);
      }
    }
    {
      bf16x8 av = ldb(&Vt[(dtile * 16 + lj) * 136 + s * 32 + lg * 8]);
#pragma unroll
      for (int i = 0; i < 9; ++i) {
        int mt = mg * 9 + i;
        kvacc[i] = mfma16(av, ldb(&strip[(mt * 16 + lj) * 40 + lg * 8]), kvacc[i]);
      }
    }
  }
  if (tid < MP) zp[((size_t)bh * NC + c) * MP + tid] = zacc;

  // coalesced kvT write via strip staging (two 32-row halves)
  const size_t base2 = ((size_t)(bh * NC + c) * 64) * MP;
  for (int half = 0; half < 2; ++half) {
    __syncthreads();
    if ((dtile >> 1) == half) {
#pragma unroll
      for (int i = 0; i < 9; ++i) {
        int mt = mg * 9 + i;
#pragma unroll
        for (int r = 0; r < 4; ++r)
          strip[((dtile & 1) * 16 + lg * 4 + r) * 296 + mt * 16 + lj] =
              f2bf(kvacc[i][r]);
      }
    }
    __syncthreads();
#pragma unroll
    for (int l = 0; l < 3; ++l) {
      int idx = tid + l * 512;
      if (idx < 1152) {
        int row = idx / 36, c8 = (idx % 36) * 8;
        *reinterpret_cast<uint4*>(&kvT[base2 + (size_t)(half * 32 + row) * MP + c8]) =
            *reinterpret_cast<const uint4*>(&strip[row * 296 + c8]);
      }
    }
  }
}

// ---------------- exclusive prefix scans over chunks (uint4 vectorized) ----------------
__global__ void scan_kv(u16* __restrict__ kvT) {
  int idx = blockIdx.x * 256 + threadIdx.x;          // 48*64*36
  if (idx >= BH * 64 * 36) return;
  int m8 = (idx % 36) * 8;
  int r = idx / 36;
  int d = r & 63, bh = r >> 6;
  u16* p = kvT + ((size_t)(bh * NC) * 64 + d) * MP + m8;
  const size_t cs = (size_t)64 * MP;
  float acc[8];
#pragma unroll
  for (int qq = 0; qq < 8; ++qq) acc[qq] = 0.f;
  for (int c = 0; c < NC; ++c) {
    uint4 raw = *reinterpret_cast<const uint4*>(p + c * cs);
    float in[8];
    unpack8v(raw, in);
    *reinterpret_cast<uint4*>(p + c * cs) = pack8(acc);
#pragma unroll
    for (int qq = 0; qq < 8; ++qq) acc[qq] += in[qq];
  }
}

__global__ void scan_z(float* __restrict__ zp) {
  int idx = blockIdx.x * 256 + threadIdx.x;          // 48*288
  if (idx >= BH * MP) return;
  int m = idx % MP, bh = idx / MP;
  float* p = zp + (size_t)bh * NC * MP + m;
  float acc = 0.f;
  for (int c = 0; c < NC; ++c) {
    float x = p[(size_t)c * MP];
    p[(size_t)c * MP] = acc;
    acc += x;
  }
}

// ---------------- stage_c (R16): padded Albuf (conflict-free) + k prefetch ----------------
// A = mask(QK^T) with phi_k recomputed per 32-row quarter; out = (A@V + Q@S_prev)/den
// Albuf padded triangular: tile-row tb pitch = 16(tb+1)+8 u16 (never 0 mod 32
// dwords); base rb(tb) = 128*tb*(tb+2). Total 10240 u16 = 20.5KB.
// arena: quarters = phik_q[32][296] + knq[32][72]; after quarter loop = Vt[64][136].
__global__ __launch_bounds__(512, 4) void stage_c(
    const float* __restrict__ v, const float* __restrict__ kk,
    const u16* __restrict__ projbf, const float* __restrict__ kmax,
    const u16* __restrict__ phiq, const u16* __restrict__ kvT,
    const float* __restrict__ zp, float* __restrict__ out) {
  __shared__ __align__(16) u16 Albuf[10240];       // 20,480 (padded triangular)
  __shared__ __align__(16) u16 arena[11776];       // 23,552
  __shared__ float zl[MP];
  __shared__ float dklq[32];
  __shared__ float qzb[128];
  __shared__ float den[128];

  u16* phik_q = arena;              // [32][296]
  u16* knq    = arena + 32 * 296;   // [32][72]

  const int tid = threadIdx.x, lane = tid & 63, wv = tid >> 6;
  const int lj = lane & 15, lg = lane >> 4;
  const int c = blockIdx.x & 31, bh = blockIdx.x >> 5;
  const int b = bh / Hn, h = bh % Hn;
  const int t0 = c * CH;
  const float kmx = kmax[bh];
  const size_t qbase = ((size_t)bh * Tn + t0) * MP;
  const size_t kvbase = ((size_t)(bh * NC + c) * 64) * MP;

  // top prefetch: qa = phi_q A-fragments for row-tile wv (used by P2 AND P4)
  bf16x8 qa[9];
#pragma unroll
  for (int ks = 0; ks < 9; ++ks)
    qa[ks] = ldb(&phiq[qbase + (size_t)(wv * 16 + lj) * MP + ks * 32 + lg * 8]);
  // prologue: k for quarter 0 into regs
  const int kt = tid >> 4, ke4 = (tid & 15) * 4;
  float4 kpre = *reinterpret_cast<const float4*>(
      &kk[(((size_t)b * Tn + t0 + kt) * Hn + h) * 64 + ke4]);
  __builtin_amdgcn_sched_barrier(0);

  if (tid < MP) zl[tid] = zp[((size_t)bh * NC + c) * MP + tid];

  for (int qq = 0; qq < 4; ++qq) {
    // write staged k -> knq bf16 + dklq (all 512 threads)
    {
      float x0 = kpre.x * DATA_NORM, x1 = kpre.y * DATA_NORM;
      float x2 = kpre.z * DATA_NORM, x3 = kpre.w * DATA_NORM;
      float ss = x0*x0 + x1*x1 + x2*x2 + x3*x3;
      *reinterpret_cast<ushort4*>(&knq[kt * 72 + ke4]) =
          make_ushort4(f2bf(x0), f2bf(x1), f2bf(x2), f2bf(x3));
      ss += __shfl_xor(ss, 1);
      ss += __shfl_xor(ss, 2);
      ss += __shfl_xor(ss, 4);
      ss += __shfl_xor(ss, 8);
      if ((tid & 15) == 0) dklq[kt] = 0.5f * ss;
    }
    __syncthreads();   // knq ready (covers zl on first iteration)

    // issue next quarter's k load; flies under P1+P2
    if (qq < 3) {
      kpre = *reinterpret_cast<const float4*>(
          &kk[(((size_t)b * Tn + t0 + (qq + 1) * 32 + kt) * Hn + h) * 64 + ke4]);
      __builtin_amdgcn_sched_barrier(0);
    }

    // P1: phi_k for quarter -> phik_q [32][296]; 36 units (2 t-tiles x 18 m-tiles)
    for (int u = wv; u < 36; u += 8) {
      int t2 = u / 18, mt = u % 18;
      bf16x8 a0 = ldb(&knq[(t2 * 16 + lj) * 72 + lg * 8]);
      bf16x8 a1 = ldb(&knq[(t2 * 16 + lj) * 72 + 32 + lg * 8]);
      const u16* br = &projbf[(mt * 16 + lj) * 64 + lg * 8];
      f32x4 z = {0.f, 0.f, 0.f, 0.f};
      z = mfma16(a0, ldb(br), z);
      z = mfma16(a1, ldb(br + 32), z);
      int m = mt * 16 + lj;
      int tq = t2 * 16 + lg * 4;
#pragma unroll
      for (int r = 0; r < 4; ++r) {
        float val = (m < Mn)
            ? RATIO * (__expf(z[r] - dklq[tq + r] - kmx) + SM_EPS) : 0.f;
        phik_q[(tq + r) * 296 + m] = f2bf(val);
      }
    }
    __syncthreads();   // phik_q ready

    // P2: wave-owns-row. Wave wv computes tiles (wv, tp) for tp in this quarter.
    const int tp0 = 2 * qq, tp1 = 2 * qq + 1;
    const bool ha = (tp0 <= wv), hb = (tp1 <= wv);
    if (ha) {
      f32x4 accA = {0.f, 0.f, 0.f, 0.f}, accB = {0.f, 0.f, 0.f, 0.f};
      __builtin_amdgcn_s_setprio(1);
#pragma unroll
      for (int ks = 0; ks < 9; ++ks) {
        int m0 = ks * 32;
        accA = mfma16(qa[ks], ldb(&phik_q[lj * 296 + m0 + lg * 8]), accA);
        if (hb)
          accB = mfma16(qa[ks], ldb(&phik_q[(16 + lj) * 296 + m0 + lg * 8]), accB);
      }
      __builtin_amdgcn_s_setprio(0);
      const int rb = 128 * wv * (wv + 2);
      const int pitch = 16 * (wv + 1) + 8;
#pragma unroll
      for (int pick = 0; pick < 2; ++pick) {
        if (pick == 1 && !hb) break;
        int tp = pick ? tp1 : tp0;
        f32x4 a = pick ? accB : accA;
        if (tp == wv) {   // diagonal tile mask
#pragma unroll
          for (int r = 0; r < 4; ++r)
            if (lj > lg * 4 + r) a[r] = 0.f;
        }
#pragma unroll
        for (int r = 0; r < 4; ++r)
          Albuf[rb + (lg * 4 + r) * pitch + tp * 16 + lj] = f2bf(a[r]);
      }
    }
    __syncthreads();   // Albuf quarter-columns done; arena free for next quarter
  }

  // stage V^T into arena (phik_q/knq dead)
  u16* Vt = arena;
#pragma unroll
  for (int l = 0; l < 4; ++l) {
    int idx = tid + l * 512;
    int t = idx >> 4, d4 = (idx & 15) * 4;
    float4 vv = *reinterpret_cast<const float4*>(
        &v[(((size_t)b * Tn + t0 + t) * Hn + h) * 64 + d4]);
    Vt[(d4 + 0) * 136 + t] = f2bf(vv.x);
    Vt[(d4 + 1) * 136 + t] = f2bf(vv.y);
    Vt[(d4 + 2) * 136 + t] = f2bf(vv.z);
    Vt[(d4 + 3) * 136 + t] = f2bf(vv.w);
  }

  // prefetch P4 first kvT quad; pin issue before the barrier
  bf16x8 kbA[4], kbB[4];
#pragma unroll
  for (int dt = 0; dt < 4; ++dt)
    kbA[dt] = ldb(&kvT[kvbase + (size_t)(dt * 16 + lj) * MP + lg * 8]);
  __builtin_amdgcn_sched_barrier(0);
  __syncthreads();   // Vt ready

  // P3: O += A @ V (triangular k-step skip, padded A rows)
  f32x4 oacc[4];
#pragma unroll
  for (int dt = 0; dt < 4; ++dt) oacc[dt] = (f32x4){0.f, 0.f, 0.f, 0.f};
  const int ksteps = (wv >> 1) + 1;
  const int rowA = 128 * wv * (wv + 2) + lj * (16 * (wv + 1) + 8);
  const bf16x8 zf = {0, 0, 0, 0, 0, 0, 0, 0};
  __builtin_amdgcn_s_setprio(1);
  for (int ks = 0; ks < ksteps; ++ks) {
    bool dead = ((wv & 1) == 0) && (ks == ksteps - 1) && (lg >= 2);
    bf16x8 af = dead ? zf : ldb(&Albuf[rowA + ks * 32 + lg * 8]);
#pragma unroll
    for (int dt = 0; dt < 4; ++dt) {
      bf16x8 bf = ldb(&Vt[(dt * 16 + lj) * 136 + ks * 32 + lg * 8]);
      oacc[dt] = mfma16(af, bf, oacc[dt]);
    }
  }
  __builtin_amdgcn_s_setprio(0);

  // P4: O += phi_q @ S_prev; B double-buffered in regs; fused qz
  float qz = 0.f;
#pragma unroll
  for (int ks = 0; ks < 9; ++ks) {
    const bf16x8* cur = (ks & 1) ? kbB : kbA;
    bf16x8* nxt = (ks & 1) ? kbA : kbB;
    if (ks < 8) {
      int m1 = (ks + 1) * 32;
#pragma unroll
      for (int dt = 0; dt < 4; ++dt)
        nxt[dt] = ldb(&kvT[kvbase + (size_t)(dt * 16 + lj) * MP + m1 + lg * 8]);
    }
#pragma unroll
    for (int e = 0; e < 8; ++e)
      qz += bf2f((u16)qa[ks][e]) * zl[ks * 32 + lg * 8 + e];
#pragma unroll
    for (int dt = 0; dt < 4; ++dt)
      oacc[dt] = mfma16(qa[ks], cur[dt], oacc[dt]);
  }
  qz += __shfl_xor(qz, 16);
  qz += __shfl_xor(qz, 32);
  if (lane < 16) qzb[wv * 16 + lane] = qz;
  __syncthreads();

  // den from padded bf16 A rows + qz + eps
  if (tid < 128) {
    int tb2 = tid >> 4;
    int Lr = 16 * (tb2 + 1);
    const u16* arow = &Albuf[128 * tb2 * (tb2 + 2) + (tid & 15) * (Lr + 8)];
    float s = qzb[tid] + N_EPS;
    for (int cc = 0; cc < Lr; cc += 8) {
      bf16x8 vv = ldb(arow + cc);
#pragma unroll
      for (int e = 0; e < 8; ++e) s += bf2f((u16)vv[e]);
    }
    den[tid] = s;
  }
  __syncthreads();

#pragma unroll
  for (int dt = 0; dt < 4; ++dt) {
#pragma unroll
    for (int r = 0; r < 4; ++r) {
      int tl = wv * 16 + lg * 4 + r;
      float o = oacc[dt][r] / den[tl];
      out[(((size_t)b * Tn + t0 + tl) * Hn + h) * 64 + dt * 16 + lj] = o;
    }
  }
}

extern "C" void kernel_launch(void* const* d_in, const int* in_sizes, int n_in,
                              void* d_out, int out_size, void* d_ws, size_t ws_size,
                              hipStream_t stream) {
  const float* q = (const float*)d_in[0];
  const float* k = (const float*)d_in[1];
  const float* v = (const float*)d_in[2];
  const float* proj = (const float*)d_in[3];
  float* out = (float*)d_out;

  char* ws = (char*)d_ws;
  const size_t phiq_b = (size_t)BH * Tn * MP * 2;        // 113,246,208
  const size_t kvT_b  = (size_t)BH * NC * 64 * MP * 2;   //  56,623,104
  const size_t zp_b   = (size_t)BH * NC * MP * 4;        //   1,769,472
  const size_t pj_b   = (size_t)MP * 64 * 2;             //      36,864

  size_t off = 0;
  u16*   phiq  = (u16*)(ws + off);  off += phiq_b;
  u16*   kvT   = (u16*)(ws + off);  off += kvT_b;
  float* zp    = (float*)(ws + off); off += zp_b;
  u16*   projbf= (u16*)(ws + off);  off += pj_b;
  float* kmax  = (float*)(ws + off);

  prep<<<72, 256, 0, stream>>>(proj, projbf, kmax);
  feat_k<<<BH * 32, 512, 0, stream>>>(k, projbf, kmax);
  feat_q<<<BH * 32, 512, 0, stream>>>(q, projbf, phiq);
  stage_a<<<BH * NC, 512, 0, stream>>>(v, k, projbf, kmax, kvT, zp);
  scan_kv<<<(BH * 64 * 36 + 255) / 256, 256, 0, stream>>>(kvT);
  scan_z<<<(BH * MP + 255) / 256, 256, 0, stream>>>(zp);
  stage_c<<<BH * NC, 512, 0, stream>>>(v, k, projbf, kmax, phiq, kvT, zp, out);
}

// Round 18
// 335.804 us; speedup vs baseline: 1.0210x; 1.0191x over previous
//
#include <hip/hip_runtime.h>
#include <hip/hip_bf16.h>

// Performer causal attention, chunked scan, MFMA bf16 everywhere.
// B=4 T=4096 H=12 E=64 M=266 (padded 288). mfma_f32_16x16x32_bf16.
// R12: wave-owns-row P2; qa[9] loaded once. R14: launch_bounds(512,4).
// R15: feat_q 4-phase staging. R16: padded Albuf + k reg-prefetch.
// R17: stage_c processes keys in TWO 64-row halves (was four 32-row
//      quarters): barriers 15->9, P1 perfectly balanced (9 units/wave),
//      longer prefetch shadow. LDS 70KB, 2 blocks/CU.

typedef unsigned short u16;
typedef __attribute__((ext_vector_type(8))) short bf16x8;   // 8 bf16 = 4 VGPR
typedef __attribute__((ext_vector_type(4))) float f32x4;

constexpr int Tn = 4096, Hn = 12;
constexpr int MP = 288;       // padded feature dim
constexpr int Mn = 266;
constexpr int CH = 128;       // chunk length
constexpr int NC = 32;        // chunks
constexpr int BH = 48;

constexpr float DATA_NORM = 0.35355339059327379f;  // 64^-0.25
constexpr float SM_EPS = 1e-4f;
constexpr float N_EPS  = 1e-6f;
constexpr float RATIO  = 0.06131393152401153f;     // 266^-0.5

__device__ __forceinline__ u16 f2bf(float f) {
  __hip_bfloat16 h = __float2bfloat16(f);
  return __builtin_bit_cast(u16, h);
}
__device__ __forceinline__ float bf2f(u16 u) {
  return __uint_as_float(((unsigned)u) << 16);
}
__device__ __forceinline__ bf16x8 ldb(const u16* p) {
  return *reinterpret_cast<const bf16x8*>(p);
}
__device__ __forceinline__ f32x4 mfma16(bf16x8 a, bf16x8 b, f32x4 c) {
  return __builtin_amdgcn_mfma_f32_16x16x32_bf16(a, b, c, 0, 0, 0);
}
__device__ __forceinline__ void atomicMaxF(float* addr, float val) {
  if (val >= 0.f) atomicMax(reinterpret_cast<int*>(addr), __float_as_int(val));
  else atomicMin(reinterpret_cast<unsigned int*>(addr), __float_as_uint(val));
}
__device__ __forceinline__ void unpack8v(uint4 r, float* f) {
  f[0] = __uint_as_float(r.x << 16);
  f[1] = __uint_as_float(r.x & 0xffff0000u);
  f[2] = __uint_as_float(r.y << 16);
  f[3] = __uint_as_float(r.y & 0xffff0000u);
  f[4] = __uint_as_float(r.z << 16);
  f[5] = __uint_as_float(r.z & 0xffff0000u);
  f[6] = __uint_as_float(r.w << 16);
  f[7] = __uint_as_float(r.w & 0xffff0000u);
}
__device__ __forceinline__ uint4 pack8(const float* f) {
  uint4 r;
  r.x = (unsigned)f2bf(f[0]) | ((unsigned)f2bf(f[1]) << 16);
  r.y = (unsigned)f2bf(f[2]) | ((unsigned)f2bf(f[3]) << 16);
  r.z = (unsigned)f2bf(f[4]) | ((unsigned)f2bf(f[5]) << 16);
  r.w = (unsigned)f2bf(f[6]) | ((unsigned)f2bf(f[7]) << 16);
  return r;
}

// ---------------- prep: projbf [288][64] bf16 zero-padded; kmax init ----------------
__global__ void prep(const float* __restrict__ proj, u16* __restrict__ projbf,
                     float* __restrict__ kmax) {
  int idx = blockIdx.x * 256 + threadIdx.x;
  if (idx < MP * 64) {
    int m = idx >> 6, e = idx & 63;
    float v = (m < Mn) ? proj[m * 64 + e] : 0.f;
    projbf[idx] = f2bf(v);
  }
  if (blockIdx.x == 0 && threadIdx.x < BH) kmax[threadIdx.x] = -3.0e38f;
}

// ---------------- feat_q (R15): 512 thr, 128 rows, 4-phase [32][296] staging ----------------
__global__ __launch_bounds__(512, 4) void feat_q(
    const float* __restrict__ q, const u16* __restrict__ projbf,
    u16* __restrict__ phiq) {
  __shared__ __align__(16) u16 xt[128 * 72];     // 18,432
  __shared__ __align__(16) u16 phib[32 * 296];   // 18,944
  __shared__ float diag[128];
  const int tid = threadIdx.x;
  const int bh = blockIdx.x >> 5, tb = blockIdx.x & 31;
  const int b = bh / Hn, h = bh % Hn;
  const int t0 = tb * 128;
  {
    const int t = tid >> 2, e0 = (tid & 3) * 16;
    const float* row = q + (((size_t)b * Tn + t0 + t) * Hn + h) * 64 + e0;
    float ss = 0.f;
#pragma unroll
    for (int q4 = 0; q4 < 4; ++q4) {
      float4 vv = *reinterpret_cast<const float4*>(row + q4 * 4);
      float x0 = vv.x * DATA_NORM, x1 = vv.y * DATA_NORM;
      float x2 = vv.z * DATA_NORM, x3 = vv.w * DATA_NORM;
      ss += x0 * x0 + x1 * x1 + x2 * x2 + x3 * x3;
      ushort4 uu = make_ushort4(f2bf(x0), f2bf(x1), f2bf(x2), f2bf(x3));
      *reinterpret_cast<ushort4*>(&xt[t * 72 + e0 + q4 * 4]) = uu;
    }
    ss += __shfl_xor(ss, 1);
    ss += __shfl_xor(ss, 2);
    if ((tid & 3) == 0) diag[t] = 0.5f * ss;
  }
  __syncthreads();
  const int lane = tid & 63, wv = tid >> 6;
  const int lj = lane & 15, lg = lane >> 4;
  bf16x8 a0 = ldb(&xt[(wv * 16 + lj) * 72 + lg * 8]);
  bf16x8 a1 = ldb(&xt[(wv * 16 + lj) * 72 + 32 + lg * 8]);
  f32x4 acc[17];
#pragma unroll
  for (int mt = 0; mt < 17; ++mt) {
    const u16* br = &projbf[(mt * 16 + lj) * 64 + lg * 8];
    f32x4 z = {0.f, 0.f, 0.f, 0.f};
    z = mfma16(a0, ldb(br), z);
    z = mfma16(a1, ldb(br + 32), z);
    acc[mt] = z;
  }
  float rmax[4] = {-3e38f, -3e38f, -3e38f, -3e38f};
#pragma unroll
  for (int mt = 0; mt < 17; ++mt) {
    int m = mt * 16 + lj;
    if (m < Mn) {
#pragma unroll
      for (int r = 0; r < 4; ++r) rmax[r] = fmaxf(rmax[r], acc[mt][r]);
    }
  }
#pragma unroll
  for (int r = 0; r < 4; ++r) {
    rmax[r] = fmaxf(rmax[r], __shfl_xor(rmax[r], 1));
    rmax[r] = fmaxf(rmax[r], __shfl_xor(rmax[r], 2));
    rmax[r] = fmaxf(rmax[r], __shfl_xor(rmax[r], 4));
    rmax[r] = fmaxf(rmax[r], __shfl_xor(rmax[r], 8));
  }
  float dg[4];
#pragma unroll
  for (int r = 0; r < 4; ++r) dg[r] = diag[wv * 16 + lg * 4 + r];
#pragma unroll
  for (int mt = 0; mt < 17; ++mt) {
    int m = mt * 16 + lj;
#pragma unroll
    for (int r = 0; r < 4; ++r) {
      float val = 0.f;
      if (m < Mn)
        val = RATIO * (__expf(acc[mt][r] - dg[r] - rmax[r]) + SM_EPS);
      acc[mt][r] = val;
    }
  }
  const uint4 z4 = make_uint4(0, 0, 0, 0);
  for (int ph = 0; ph < 4; ++ph) {
    __syncthreads();   // phib free
    if ((wv >> 1) == ph) {
#pragma unroll
      for (int mt = 0; mt < 17; ++mt) {
#pragma unroll
        for (int r = 0; r < 4; ++r)
          phib[((wv & 1) * 16 + lg * 4 + r) * 296 + mt * 16 + lj] =
              f2bf(acc[mt][r]);
      }
    }
    __syncthreads();
    u16* ob2 = phiq + ((size_t)bh * Tn + t0 + ph * 32) * MP;
#pragma unroll
    for (int l = 0; l < 3; ++l) {
      int idx = tid + l * 512;
      if (idx < 1152) {
        int row = idx / 36, c8 = (idx % 36) * 8;
        uint4 o = (c8 >= 272) ? z4
                              : *reinterpret_cast<const uint4*>(&phib[row * 296 + c8]);
        *reinterpret_cast<uint4*>(&ob2[(size_t)row * MP + c8]) = o;
      }
    }
  }
}

// ---------------- feat_k (R9): 512 thr, 128 rows, global max only ----------------
__global__ __launch_bounds__(512) void feat_k(
    const float* __restrict__ k, const u16* __restrict__ projbf,
    float* __restrict__ kmax) {
  __shared__ __align__(16) u16 xt[128 * 72];
  __shared__ float wred[8];
  const int tid = threadIdx.x;
  const int bh = blockIdx.x >> 5, tb = blockIdx.x & 31;
  const int b = bh / Hn, h = bh % Hn;
  const int t0 = tb * 128;
  {
    const int t = tid >> 2, e0 = (tid & 3) * 16;
    const float* row = k + (((size_t)b * Tn + t0 + t) * Hn + h) * 64 + e0;
#pragma unroll
    for (int q4 = 0; q4 < 4; ++q4) {
      float4 vv = *reinterpret_cast<const float4*>(row + q4 * 4);
      ushort4 uu = make_ushort4(f2bf(vv.x * DATA_NORM), f2bf(vv.y * DATA_NORM),
                                f2bf(vv.z * DATA_NORM), f2bf(vv.w * DATA_NORM));
      *reinterpret_cast<ushort4*>(&xt[t * 72 + e0 + q4 * 4]) = uu;
    }
  }
  __syncthreads();
  const int lane = tid & 63, wv = tid >> 6;
  const int lj = lane & 15, lg = lane >> 4;
  bf16x8 a0 = ldb(&xt[(wv * 16 + lj) * 72 + lg * 8]);
  bf16x8 a1 = ldb(&xt[(wv * 16 + lj) * 72 + 32 + lg * 8]);
  float mx = -3e38f;
#pragma unroll
  for (int mt = 0; mt < 17; ++mt) {
    const u16* br = &projbf[(mt * 16 + lj) * 64 + lg * 8];
    f32x4 z = {0.f, 0.f, 0.f, 0.f};
    z = mfma16(a0, ldb(br), z);
    z = mfma16(a1, ldb(br + 32), z);
    int m = mt * 16 + lj;
    if (m < Mn)
      mx = fmaxf(mx, fmaxf(fmaxf(z[0], z[1]), fmaxf(z[2], z[3])));
  }
  mx = fmaxf(mx, __shfl_xor(mx, 1));
  mx = fmaxf(mx, __shfl_xor(mx, 2));
  mx = fmaxf(mx, __shfl_xor(mx, 4));
  mx = fmaxf(mx, __shfl_xor(mx, 8));
  mx = fmaxf(mx, __shfl_xor(mx, 16));
  mx = fmaxf(mx, __shfl_xor(mx, 32));
  if (lane == 0) wred[wv] = mx;
  __syncthreads();
  if (tid == 0) {
    float m2 = wred[0];
#pragma unroll
    for (int i = 1; i < 8; ++i) m2 = fmaxf(m2, wred[i]);
    atomicMaxF(&kmax[bh], m2);
  }
}

// ---------------- stage_a: KV^T partial + z partial; coalesced kvT write ----------------
__global__ __launch_bounds__(512) void stage_a(
    const float* __restrict__ v, const float* __restrict__ kk,
    const u16* __restrict__ projbf, const float* __restrict__ kmax,
    u16* __restrict__ kvT, float* __restrict__ zp) {
  __shared__ __align__(16) u16 knl[128 * 72];     // 18,432
  __shared__ __align__(16) u16 Vt[64 * 136];      // 17,408  (V^T [d][t])
  __shared__ __align__(16) u16 strip[288 * 40];   // 23,040  (phi_k^T, then kv staging)
  __shared__ float dkl[128];
  const int tid = threadIdx.x, lane = tid & 63, wv = tid >> 6;
  const int lj = lane & 15, lg = lane >> 4;
  const int c = blockIdx.x & 31, bh = blockIdx.x >> 5;
  const int b = bh / Hn, h = bh % Hn;
  const int t0 = c * CH;
  const float kmx = kmax[bh];

#pragma unroll
  for (int l = 0; l < 2; ++l) {
    int idx = tid + l * 512;
    int t = idx >> 3, e8 = (idx & 7) * 8;
    const float* kr = &kk[(((size_t)b * Tn + t0 + t) * Hn + h) * 64 + e8];
    float4 u0 = *reinterpret_cast<const float4*>(kr);
    float4 u1 = *reinterpret_cast<const float4*>(kr + 4);
    float x0 = u0.x * DATA_NORM, x1 = u0.y * DATA_NORM;
    float x2 = u0.z * DATA_NORM, x3 = u0.w * DATA_NORM;
    float x4 = u1.x * DATA_NORM, x5 = u1.y * DATA_NORM;
    float x6 = u1.z * DATA_NORM, x7 = u1.w * DATA_NORM;
    float ss = x0*x0 + x1*x1 + x2*x2 + x3*x3 + x4*x4 + x5*x5 + x6*x6 + x7*x7;
    *reinterpret_cast<ushort4*>(&knl[t * 72 + e8]) =
        make_ushort4(f2bf(x0), f2bf(x1), f2bf(x2), f2bf(x3));
    *reinterpret_cast<ushort4*>(&knl[t * 72 + e8 + 4]) =
        make_ushort4(f2bf(x4), f2bf(x5), f2bf(x6), f2bf(x7));
    ss += __shfl_xor(ss, 1);
    ss += __shfl_xor(ss, 2);
    ss += __shfl_xor(ss, 4);
    if ((tid & 7) == 0) dkl[t] = 0.5f * ss;
  }
#pragma unroll
  for (int l = 0; l < 4; ++l) {   // V -> V^T LDS bf16
    int idx = tid + l * 512;
    int t = idx >> 4, d4 = (idx & 15) * 4;
    float4 vv = *reinterpret_cast<const float4*>(
        &v[(((size_t)b * Tn + t0 + t) * Hn + h) * 64 + d4]);
    Vt[(d4 + 0) * 136 + t] = f2bf(vv.x);
    Vt[(d4 + 1) * 136 + t] = f2bf(vv.y);
    Vt[(d4 + 2) * 136 + t] = f2bf(vv.z);
    Vt[(d4 + 3) * 136 + t] = f2bf(vv.w);
  }

  float zacc = 0.f;
  f32x4 kvacc[9];
#pragma unroll
  for (int i = 0; i < 9; ++i) kvacc[i] = (f32x4){0.f, 0.f, 0.f, 0.f};
  const int dtile = wv & 3, mg = wv >> 2;
  __syncthreads();

  for (int s = 0; s < 4; ++s) {
    if (s) __syncthreads();
#pragma unroll
    for (int i = 0; i < 5; ++i) {
      int idx = wv + 8 * i;
      if (idx < 36) {
        int mt = idx % 18, th = idx / 18;
        const u16* ar = &projbf[(mt * 16 + lj) * 64 + lg * 8];
        int trow = s * 32 + th * 16 + lj;
        const u16* br = &knl[trow * 72 + lg * 8];
        f32x4 z = {0.f, 0.f, 0.f, 0.f};
        z = mfma16(ldb(ar), ldb(br), z);
        z = mfma16(ldb(ar + 32), ldb(br + 32), z);
        float dgk = dkl[trow];
#pragma unroll
        for (int r = 0; r < 4; ++r) {
          int m = mt * 16 + lg * 4 + r;
          float val = (m < Mn) ? RATIO * (__expf(z[r] - dgk - kmx) + SM_EPS) : 0.f;
          strip[m * 40 + th * 16 + lj] = f2bf(val);
        }
      }
    }
    __syncthreads();
    if (tid < MP) {
      const u16* srow = &strip[tid * 40];
#pragma unroll
      for (int o = 0; o < 32; o += 8) {
        bf16x8 vv = ldb(srow + o);
#pragma unroll
        for (int e = 0; e < 8; ++e) zacc += bf2f((u16)vv[e]);
      }
    }
    {
      bf16x8 av = ldb(&Vt[(dtile * 16 + lj) * 136 + s * 32 + lg * 8]);
#pragma unroll
      for (int i = 0; i < 9; ++i) {
        int mt = mg * 9 + i;
        kvacc[i] = mfma16(av, ldb(&strip[(mt * 16 + lj) * 40 + lg * 8]), kvacc[i]);
      }
    }
  }
  if (tid < MP) zp[((size_t)bh * NC + c) * MP + tid] = zacc;

  // coalesced kvT write via strip staging (two 32-row halves)
  const size_t base2 = ((size_t)(bh * NC + c) * 64) * MP;
  for (int half = 0; half < 2; ++half) {
    __syncthreads();
    if ((dtile >> 1) == half) {
#pragma unroll
      for (int i = 0; i < 9; ++i) {
        int mt = mg * 9 + i;
#pragma unroll
        for (int r = 0; r < 4; ++r)
          strip[((dtile & 1) * 16 + lg * 4 + r) * 296 + mt * 16 + lj] =
              f2bf(kvacc[i][r]);
      }
    }
    __syncthreads();
#pragma unroll
    for (int l = 0; l < 3; ++l) {
      int idx = tid + l * 512;
      if (idx < 1152) {
        int row = idx / 36, c8 = (idx % 36) * 8;
        *reinterpret_cast<uint4*>(&kvT[base2 + (size_t)(half * 32 + row) * MP + c8]) =
            *reinterpret_cast<const uint4*>(&strip[row * 296 + c8]);
      }
    }
  }
}

// ---------------- exclusive prefix scans over chunks (uint4 vectorized) ----------------
__global__ void scan_kv(u16* __restrict__ kvT) {
  int idx = blockIdx.x * 256 + threadIdx.x;          // 48*64*36
  if (idx >= BH * 64 * 36) return;
  int m8 = (idx % 36) * 8;
  int r = idx / 36;
  int d = r & 63, bh = r >> 6;
  u16* p = kvT + ((size_t)(bh * NC) * 64 + d) * MP + m8;
  const size_t cs = (size_t)64 * MP;
  float acc[8];
#pragma unroll
  for (int qq = 0; qq < 8; ++qq) acc[qq] = 0.f;
  for (int c = 0; c < NC; ++c) {
    uint4 raw = *reinterpret_cast<const uint4*>(p + c * cs);
    float in[8];
    unpack8v(raw, in);
    *reinterpret_cast<uint4*>(p + c * cs) = pack8(acc);
#pragma unroll
    for (int qq = 0; qq < 8; ++qq) acc[qq] += in[qq];
  }
}

__global__ void scan_z(float* __restrict__ zp) {
  int idx = blockIdx.x * 256 + threadIdx.x;          // 48*288
  if (idx >= BH * MP) return;
  int m = idx % MP, bh = idx / MP;
  float* p = zp + (size_t)bh * NC * MP + m;
  float acc = 0.f;
  for (int c = 0; c < NC; ++c) {
    float x = p[(size_t)c * MP];
    p[(size_t)c * MP] = acc;
    acc += x;
  }
}

// ---------------- stage_c (R17): two 64-row halves, padded Albuf, k prefetch ----------------
// A = mask(QK^T) with phi_k recomputed per 64-row HALF; out = (A@V + Q@S_prev)/den
// Albuf padded triangular: tile-row tb pitch = 16(tb+1)+8 u16; base 128*tb*(tb+2).
// arena: halves = phik_h[64][296] + knh[64][72] (47.1KB); after = Vt[64][136].
__global__ __launch_bounds__(512, 4) void stage_c(
    const float* __restrict__ v, const float* __restrict__ kk,
    const u16* __restrict__ projbf, const float* __restrict__ kmax,
    const u16* __restrict__ phiq, const u16* __restrict__ kvT,
    const float* __restrict__ zp, float* __restrict__ out) {
  __shared__ __align__(16) u16 Albuf[10240];       // 20,480 (padded triangular)
  __shared__ __align__(16) u16 arena[23552];       // 47,104
  __shared__ float zl[MP];
  __shared__ float dklh[64];
  __shared__ float qzb[128];
  __shared__ float den[128];

  u16* phik_h = arena;              // [64][296]
  u16* knh    = arena + 64 * 296;   // [64][72]

  const int tid = threadIdx.x, lane = tid & 63, wv = tid >> 6;
  const int lj = lane & 15, lg = lane >> 4;
  const int c = blockIdx.x & 31, bh = blockIdx.x >> 5;
  const int b = bh / Hn, h = bh % Hn;
  const int t0 = c * CH;
  const float kmx = kmax[bh];
  const size_t qbase = ((size_t)bh * Tn + t0) * MP;
  const size_t kvbase = ((size_t)(bh * NC + c) * 64) * MP;

  // top prefetch: qa = phi_q A-fragments for row-tile wv (used by P2 AND P4)
  bf16x8 qa[9];
#pragma unroll
  for (int ks = 0; ks < 9; ++ks)
    qa[ks] = ldb(&phiq[qbase + (size_t)(wv * 16 + lj) * MP + ks * 32 + lg * 8]);
  // prologue: k for half 0 into regs (64 rows x 64 elems; 8 f32/thread)
  const int kt = tid >> 3, ke8 = (tid & 7) * 8;
  const float* kb0 = &kk[(((size_t)b * Tn + t0 + kt) * Hn + h) * 64 + ke8];
  float4 kp0 = *reinterpret_cast<const float4*>(kb0);
  float4 kp1 = *reinterpret_cast<const float4*>(kb0 + 4);
  __builtin_amdgcn_sched_barrier(0);

  if (tid < MP) zl[tid] = zp[((size_t)bh * NC + c) * MP + tid];

  for (int hh = 0; hh < 2; ++hh) {
    // write staged k -> knh bf16 + dklh (all 512 threads, 8 elems each)
    {
      float x0 = kp0.x * DATA_NORM, x1 = kp0.y * DATA_NORM;
      float x2 = kp0.z * DATA_NORM, x3 = kp0.w * DATA_NORM;
      float x4 = kp1.x * DATA_NORM, x5 = kp1.y * DATA_NORM;
      float x6 = kp1.z * DATA_NORM, x7 = kp1.w * DATA_NORM;
      float ss = x0*x0 + x1*x1 + x2*x2 + x3*x3 + x4*x4 + x5*x5 + x6*x6 + x7*x7;
      *reinterpret_cast<ushort4*>(&knh[kt * 72 + ke8]) =
          make_ushort4(f2bf(x0), f2bf(x1), f2bf(x2), f2bf(x3));
      *reinterpret_cast<ushort4*>(&knh[kt * 72 + ke8 + 4]) =
          make_ushort4(f2bf(x4), f2bf(x5), f2bf(x6), f2bf(x7));
      ss += __shfl_xor(ss, 1);
      ss += __shfl_xor(ss, 2);
      ss += __shfl_xor(ss, 4);
      if ((tid & 7) == 0) dklh[kt] = 0.5f * ss;
    }
    __syncthreads();   // knh ready (covers zl on first iteration)

    // issue next half's k load; flies under P1+P2
    if (hh == 0) {
      const float* kb1 = &kk[(((size_t)b * Tn + t0 + 64 + kt) * Hn + h) * 64 + ke8];
      kp0 = *reinterpret_cast<const float4*>(kb1);
      kp1 = *reinterpret_cast<const float4*>(kb1 + 4);
      __builtin_amdgcn_sched_barrier(0);
    }

    // P1: phi_k for half -> phik_h [64][296]; 72 units (4 t-tiles x 18 m-tiles),
    // exactly 9 per wave.
    for (int u = wv; u < 72; u += 8) {
      int t4 = u / 18, mt = u % 18;
      bf16x8 a0 = ldb(&knh[(t4 * 16 + lj) * 72 + lg * 8]);
      bf16x8 a1 = ldb(&knh[(t4 * 16 + lj) * 72 + 32 + lg * 8]);
      const u16* br = &projbf[(mt * 16 + lj) * 64 + lg * 8];
      f32x4 z = {0.f, 0.f, 0.f, 0.f};
      z = mfma16(a0, ldb(br), z);
      z = mfma16(a1, ldb(br + 32), z);
      int m = mt * 16 + lj;
      int tq = t4 * 16 + lg * 4;
#pragma unroll
      for (int r = 0; r < 4; ++r) {
        float val = (m < Mn)
            ? RATIO * (__expf(z[r] - dklh[tq + r] - kmx) + SM_EPS) : 0.f;
        phik_h[(tq + r) * 296 + m] = f2bf(val);
      }
    }
    __syncthreads();   // phik_h ready

    // P2: wave-owns-row; two tp-pairs per half (tp in {4hh..4hh+3}, tp<=wv)
    const int tpb = 4 * hh;
#pragma unroll
    for (int pr = 0; pr < 2; ++pr) {
      const int tp0 = tpb + 2 * pr, tp1 = tp0 + 1;
      const bool ha = (tp0 <= wv), hb = (tp1 <= wv);
      if (!ha) break;
      const int lr0 = (2 * pr) * 16, lr1 = (2 * pr + 1) * 16;   // local key rows
      f32x4 accA = {0.f, 0.f, 0.f, 0.f}, accB = {0.f, 0.f, 0.f, 0.f};
      __builtin_amdgcn_s_setprio(1);
#pragma unroll
      for (int ks = 0; ks < 9; ++ks) {
        int m0 = ks * 32;
        accA = mfma16(qa[ks], ldb(&phik_h[(lr0 + lj) * 296 + m0 + lg * 8]), accA);
        if (hb)
          accB = mfma16(qa[ks], ldb(&phik_h[(lr1 + lj) * 296 + m0 + lg * 8]), accB);
      }
      __builtin_amdgcn_s_setprio(0);
      const int rb = 128 * wv * (wv + 2);
      const int pitch = 16 * (wv + 1) + 8;
#pragma unroll
      for (int pick = 0; pick < 2; ++pick) {
        if (pick == 1 && !hb) break;
        int tp = pick ? tp1 : tp0;
        f32x4 a = pick ? accB : accA;
        if (tp == wv) {   // diagonal tile mask
#pragma unroll
          for (int r = 0; r < 4; ++r)
            if (lj > lg * 4 + r) a[r] = 0.f;
        }
#pragma unroll
        for (int r = 0; r < 4; ++r)
          Albuf[rb + (lg * 4 + r) * pitch + tp * 16 + lj] = f2bf(a[r]);
      }
    }
    __syncthreads();   // Albuf half-columns done; arena free for next half
  }

  // stage V^T into arena (phik_h/knh dead)
  u16* Vt = arena;
#pragma unroll
  for (int l = 0; l < 4; ++l) {
    int idx = tid + l * 512;
    int t = idx >> 4, d4 = (idx & 15) * 4;
    float4 vv = *reinterpret_cast<const float4*>(
        &v[(((size_t)b * Tn + t0 + t) * Hn + h) * 64 + d4]);
    Vt[(d4 + 0) * 136 + t] = f2bf(vv.x);
    Vt[(d4 + 1) * 136 + t] = f2bf(vv.y);
    Vt[(d4 + 2) * 136 + t] = f2bf(vv.z);
    Vt[(d4 + 3) * 136 + t] = f2bf(vv.w);
  }

  // prefetch P4 first kvT quad; pin issue before the barrier
  bf16x8 kbA[4], kbB[4];
#pragma unroll
  for (int dt = 0; dt < 4; ++dt)
    kbA[dt] = ldb(&kvT[kvbase + (size_t)(dt * 16 + lj) * MP + lg * 8]);
  __builtin_amdgcn_sched_barrier(0);
  __syncthreads();   // Vt ready

  // P3: O += A @ V (triangular k-step skip, padded A rows)
  f32x4 oacc[4];
#pragma unroll
  for (int dt = 0; dt < 4; ++dt) oacc[dt] = (f32x4){0.f, 0.f, 0.f, 0.f};
  const int ksteps = (wv >> 1) + 1;
  const int rowA = 128 * wv * (wv + 2) + lj * (16 * (wv + 1) + 8);
  const bf16x8 zf = {0, 0, 0, 0, 0, 0, 0, 0};
  __builtin_amdgcn_s_setprio(1);
  for (int ks = 0; ks < ksteps; ++ks) {
    bool dead = ((wv & 1) == 0) && (ks == ksteps - 1) && (lg >= 2);
    bf16x8 af = dead ? zf : ldb(&Albuf[rowA + ks * 32 + lg * 8]);
#pragma unroll
    for (int dt = 0; dt < 4; ++dt) {
      bf16x8 bf = ldb(&Vt[(dt * 16 + lj) * 136 + ks * 32 + lg * 8]);
      oacc[dt] = mfma16(af, bf, oacc[dt]);
    }
  }
  __builtin_amdgcn_s_setprio(0);

  // P4: O += phi_q @ S_prev; B double-buffered in regs; fused qz
  float qz = 0.f;
#pragma unroll
  for (int ks = 0; ks < 9; ++ks) {
    const bf16x8* cur = (ks & 1) ? kbB : kbA;
    bf16x8* nxt = (ks & 1) ? kbA : kbB;
    if (ks < 8) {
      int m1 = (ks + 1) * 32;
#pragma unroll
      for (int dt = 0; dt < 4; ++dt)
        nxt[dt] = ldb(&kvT[kvbase + (size_t)(dt * 16 + lj) * MP + m1 + lg * 8]);
    }
#pragma unroll
    for (int e = 0; e < 8; ++e)
      qz += bf2f((u16)qa[ks][e]) * zl[ks * 32 + lg * 8 + e];
#pragma unroll
    for (int dt = 0; dt < 4; ++dt)
      oacc[dt] = mfma16(qa[ks], cur[dt], oacc[dt]);
  }
  qz += __shfl_xor(qz, 16);
  qz += __shfl_xor(qz, 32);
  if (lane < 16) qzb[wv * 16 + lane] = qz;
  __syncthreads();

  // den from padded bf16 A rows + qz + eps
  if (tid < 128) {
    int tb2 = tid >> 4;
    int Lr = 16 * (tb2 + 1);
    const u16* arow = &Albuf[128 * tb2 * (tb2 + 2) + (tid & 15) * (Lr + 8)];
    float s = qzb[tid] + N_EPS;
    for (int cc = 0; cc < Lr; cc += 8) {
      bf16x8 vv = ldb(arow + cc);
#pragma unroll
      for (int e = 0; e < 8; ++e) s += bf2f((u16)vv[e]);
    }
    den[tid] = s;
  }
  __syncthreads();

#pragma unroll
  for (int dt = 0; dt < 4; ++dt) {
#pragma unroll
    for (int r = 0; r < 4; ++r) {
      int tl = wv * 16 + lg * 4 + r;
      float o = oacc[dt][r] / den[tl];
      out[(((size_t)b * Tn + t0 + tl) * Hn + h) * 64 + dt * 16 + lj] = o;
    }
  }
}

extern "C" void kernel_launch(void* const* d_in, const int* in_sizes, int n_in,
                              void* d_out, int out_size, void* d_ws, size_t ws_size,
                              hipStream_t stream) {
  const float* q = (const float*)d_in[0];
  const float* k = (const float*)d_in[1];
  const float* v = (const float*)d_in[2];
  const float* proj = (const float*)d_in[3];
  float* out = (float*)d_out;

  char* ws = (char*)d_ws;
  const size_t phiq_b = (size_t)BH * Tn * MP * 2;        // 113,246,208
  const size_t kvT_b  = (size_t)BH * NC * 64 * MP * 2;   //  56,623,104
  const size_t zp_b   = (size_t)BH * NC * MP * 4;        //   1,769,472
  const size_t pj_b   = (size_t)MP * 64 * 2;             //      36,864

  size_t off = 0;
  u16*   phiq  = (u16*)(ws + off);  off += phiq_b;
  u16*   kvT   = (u16*)(ws + off);  off += kvT_b;
  float* zp    = (float*)(ws + off); off += zp_b;
  u16*   projbf= (u16*)(ws + off);  off += pj_b;
  float* kmax  = (float*)(ws + off);

  prep<<<72, 256, 0, stream>>>(proj, projbf, kmax);
  feat_k<<<BH * 32, 512, 0, stream>>>(k, projbf, kmax);
  feat_q<<<BH * 32, 512, 0, stream>>>(q, projbf, phiq);
  stage_a<<<BH * NC, 512, 0, stream>>>(v, k, projbf, kmax, kvT, zp);
  scan_kv<<<(BH * 64 * 36 + 255) / 256, 256, 0, stream>>>(kvT);
  scan_z<<<(BH * MP + 255) / 256, 256, 0, stream>>>(zp);
  stage_c<<<BH * NC, 512, 0, stream>>>(v, k, projbf, kmax, phiq, kvT, zp, out);
}

// Round 19
// 326.883 us; speedup vs baseline: 1.0489x; 1.0273x over previous
//
#include <hip/hip_runtime.h>
#include <hip/hip_bf16.h>

// Performer causal attention, chunked scan, MFMA bf16 everywhere.
// B=4 T=4096 H=12 E=64 M=266 (padded 288). mfma_f32_16x16x32_bf16.
// R17: stage_c two 64-row halves, padded Albuf, k reg-prefetch (135->128us).
// R18: grid fusion to kill kernel-boundary drains: featqk = feat_q|feat_k in
//      one launch (independent work, union'd LDS arena); scan_all = scan_kv|
//      scan_z. Kernel bodies byte-identical to R17. 5 launches (was 7).

typedef unsigned short u16;
typedef __attribute__((ext_vector_type(8))) short bf16x8;   // 8 bf16 = 4 VGPR
typedef __attribute__((ext_vector_type(4))) float f32x4;

constexpr int Tn = 4096, Hn = 12;
constexpr int MP = 288;       // padded feature dim
constexpr int Mn = 266;
constexpr int CH = 128;       // chunk length
constexpr int NC = 32;        // chunks
constexpr int BH = 48;

constexpr float DATA_NORM = 0.35355339059327379f;  // 64^-0.25
constexpr float SM_EPS = 1e-4f;
constexpr float N_EPS  = 1e-6f;
constexpr float RATIO  = 0.06131393152401153f;     // 266^-0.5

__device__ __forceinline__ u16 f2bf(float f) {
  __hip_bfloat16 h = __float2bfloat16(f);
  return __builtin_bit_cast(u16, h);
}
__device__ __forceinline__ float bf2f(u16 u) {
  return __uint_as_float(((unsigned)u) << 16);
}
__device__ __forceinline__ bf16x8 ldb(const u16* p) {
  return *reinterpret_cast<const bf16x8*>(p);
}
__device__ __forceinline__ f32x4 mfma16(bf16x8 a, bf16x8 b, f32x4 c) {
  return __builtin_amdgcn_mfma_f32_16x16x32_bf16(a, b, c, 0, 0, 0);
}
__device__ __forceinline__ void atomicMaxF(float* addr, float val) {
  if (val >= 0.f) atomicMax(reinterpret_cast<int*>(addr), __float_as_int(val));
  else atomicMin(reinterpret_cast<unsigned int*>(addr), __float_as_uint(val));
}
__device__ __forceinline__ void unpack8v(uint4 r, float* f) {
  f[0] = __uint_as_float(r.x << 16);
  f[1] = __uint_as_float(r.x & 0xffff0000u);
  f[2] = __uint_as_float(r.y << 16);
  f[3] = __uint_as_float(r.y & 0xffff0000u);
  f[4] = __uint_as_float(r.z << 16);
  f[5] = __uint_as_float(r.z & 0xffff0000u);
  f[6] = __uint_as_float(r.w << 16);
  f[7] = __uint_as_float(r.w & 0xffff0000u);
}
__device__ __forceinline__ uint4 pack8(const float* f) {
  uint4 r;
  r.x = (unsigned)f2bf(f[0]) | ((unsigned)f2bf(f[1]) << 16);
  r.y = (unsigned)f2bf(f[2]) | ((unsigned)f2bf(f[3]) << 16);
  r.z = (unsigned)f2bf(f[4]) | ((unsigned)f2bf(f[5]) << 16);
  r.w = (unsigned)f2bf(f[6]) | ((unsigned)f2bf(f[7]) << 16);
  return r;
}

// ---------------- prep: projbf [288][64] bf16 zero-padded; kmax init ----------------
__global__ void prep(const float* __restrict__ proj, u16* __restrict__ projbf,
                     float* __restrict__ kmax) {
  int idx = blockIdx.x * 256 + threadIdx.x;
  if (idx < MP * 64) {
    int m = idx >> 6, e = idx & 63;
    float v = (m < Mn) ? proj[m * 64 + e] : 0.f;
    projbf[idx] = f2bf(v);
  }
  if (blockIdx.x == 0 && threadIdx.x < BH) kmax[threadIdx.x] = -3.0e38f;
}

// ---------------- featqk (R18): fused feat_q | feat_k, union'd LDS arena ----------------
// blocks [0, BH*32): feat_q body (R15, byte-identical math)
// blocks [BH*32, 2*BH*32): feat_k body (R9, byte-identical math)
__global__ __launch_bounds__(512, 4) void featqk(
    const float* __restrict__ q, const float* __restrict__ k,
    const u16* __restrict__ projbf, u16* __restrict__ phiq,
    float* __restrict__ kmax) {
  __shared__ __align__(16) u16 arena[128 * 72 + 32 * 296];  // xt + phib (37.4KB)
  __shared__ float diag[128];
  __shared__ float wred[8];
  u16* xt   = arena;               // [128][72]
  u16* phib = arena + 128 * 72;    // [32][296] (feat_q only)

  const int tid = threadIdx.x;
  const int bid = blockIdx.x;
  const int lane = tid & 63, wv = tid >> 6;
  const int lj = lane & 15, lg = lane >> 4;

  if (bid < BH * 32) {
    // ================= feat_q =================
    const int bh = bid >> 5, tb = bid & 31;
    const int b = bh / Hn, h = bh % Hn;
    const int t0 = tb * 128;
    {
      const int t = tid >> 2, e0 = (tid & 3) * 16;
      const float* row = q + (((size_t)b * Tn + t0 + t) * Hn + h) * 64 + e0;
      float ss = 0.f;
#pragma unroll
      for (int q4 = 0; q4 < 4; ++q4) {
        float4 vv = *reinterpret_cast<const float4*>(row + q4 * 4);
        float x0 = vv.x * DATA_NORM, x1 = vv.y * DATA_NORM;
        float x2 = vv.z * DATA_NORM, x3 = vv.w * DATA_NORM;
        ss += x0 * x0 + x1 * x1 + x2 * x2 + x3 * x3;
        ushort4 uu = make_ushort4(f2bf(x0), f2bf(x1), f2bf(x2), f2bf(x3));
        *reinterpret_cast<ushort4*>(&xt[t * 72 + e0 + q4 * 4]) = uu;
      }
      ss += __shfl_xor(ss, 1);
      ss += __shfl_xor(ss, 2);
      if ((tid & 3) == 0) diag[t] = 0.5f * ss;
    }
    __syncthreads();
    bf16x8 a0 = ldb(&xt[(wv * 16 + lj) * 72 + lg * 8]);
    bf16x8 a1 = ldb(&xt[(wv * 16 + lj) * 72 + 32 + lg * 8]);
    f32x4 acc[17];
#pragma unroll
    for (int mt = 0; mt < 17; ++mt) {
      const u16* br = &projbf[(mt * 16 + lj) * 64 + lg * 8];
      f32x4 z = {0.f, 0.f, 0.f, 0.f};
      z = mfma16(a0, ldb(br), z);
      z = mfma16(a1, ldb(br + 32), z);
      acc[mt] = z;
    }
    float rmax[4] = {-3e38f, -3e38f, -3e38f, -3e38f};
#pragma unroll
    for (int mt = 0; mt < 17; ++mt) {
      int m = mt * 16 + lj;
      if (m < Mn) {
#pragma unroll
        for (int r = 0; r < 4; ++r) rmax[r] = fmaxf(rmax[r], acc[mt][r]);
      }
    }
#pragma unroll
    for (int r = 0; r < 4; ++r) {
      rmax[r] = fmaxf(rmax[r], __shfl_xor(rmax[r], 1));
      rmax[r] = fmaxf(rmax[r], __shfl_xor(rmax[r], 2));
      rmax[r] = fmaxf(rmax[r], __shfl_xor(rmax[r], 4));
      rmax[r] = fmaxf(rmax[r], __shfl_xor(rmax[r], 8));
    }
    float dg[4];
#pragma unroll
    for (int r = 0; r < 4; ++r) dg[r] = diag[wv * 16 + lg * 4 + r];
#pragma unroll
    for (int mt = 0; mt < 17; ++mt) {
      int m = mt * 16 + lj;
#pragma unroll
      for (int r = 0; r < 4; ++r) {
        float val = 0.f;
        if (m < Mn)
          val = RATIO * (__expf(acc[mt][r] - dg[r] - rmax[r]) + SM_EPS);
        acc[mt][r] = val;
      }
    }
    const uint4 z4 = make_uint4(0, 0, 0, 0);
    for (int ph = 0; ph < 4; ++ph) {
      __syncthreads();   // phib free
      if ((wv >> 1) == ph) {
#pragma unroll
        for (int mt = 0; mt < 17; ++mt) {
#pragma unroll
          for (int r = 0; r < 4; ++r)
            phib[((wv & 1) * 16 + lg * 4 + r) * 296 + mt * 16 + lj] =
                f2bf(acc[mt][r]);
        }
      }
      __syncthreads();
      u16* ob2 = phiq + ((size_t)bh * Tn + t0 + ph * 32) * MP;
#pragma unroll
      for (int l = 0; l < 3; ++l) {
        int idx = tid + l * 512;
        if (idx < 1152) {
          int row = idx / 36, c8 = (idx % 36) * 8;
          uint4 o = (c8 >= 272) ? z4
                                : *reinterpret_cast<const uint4*>(&phib[row * 296 + c8]);
          *reinterpret_cast<uint4*>(&ob2[(size_t)row * MP + c8]) = o;
        }
      }
    }
  } else {
    // ================= feat_k =================
    const int fb = bid - BH * 32;
    const int bh = fb >> 5, tb = fb & 31;
    const int b = bh / Hn, h = bh % Hn;
    const int t0 = tb * 128;
    {
      const int t = tid >> 2, e0 = (tid & 3) * 16;
      const float* row = k + (((size_t)b * Tn + t0 + t) * Hn + h) * 64 + e0;
#pragma unroll
      for (int q4 = 0; q4 < 4; ++q4) {
        float4 vv = *reinterpret_cast<const float4*>(row + q4 * 4);
        ushort4 uu = make_ushort4(f2bf(vv.x * DATA_NORM), f2bf(vv.y * DATA_NORM),
                                  f2bf(vv.z * DATA_NORM), f2bf(vv.w * DATA_NORM));
        *reinterpret_cast<ushort4*>(&xt[t * 72 + e0 + q4 * 4]) = uu;
      }
    }
    __syncthreads();
    bf16x8 a0 = ldb(&xt[(wv * 16 + lj) * 72 + lg * 8]);
    bf16x8 a1 = ldb(&xt[(wv * 16 + lj) * 72 + 32 + lg * 8]);
    float mx = -3e38f;
#pragma unroll
    for (int mt = 0; mt < 17; ++mt) {
      const u16* br = &projbf[(mt * 16 + lj) * 64 + lg * 8];
      f32x4 z = {0.f, 0.f, 0.f, 0.f};
      z = mfma16(a0, ldb(br), z);
      z = mfma16(a1, ldb(br + 32), z);
      int m = mt * 16 + lj;
      if (m < Mn)
        mx = fmaxf(mx, fmaxf(fmaxf(z[0], z[1]), fmaxf(z[2], z[3])));
    }
    mx = fmaxf(mx, __shfl_xor(mx, 1));
    mx = fmaxf(mx, __shfl_xor(mx, 2));
    mx = fmaxf(mx, __shfl_xor(mx, 4));
    mx = fmaxf(mx, __shfl_xor(mx, 8));
    mx = fmaxf(mx, __shfl_xor(mx, 16));
    mx = fmaxf(mx, __shfl_xor(mx, 32));
    if (lane == 0) wred[wv] = mx;
    __syncthreads();
    if (tid == 0) {
      float m2 = wred[0];
#pragma unroll
      for (int i = 1; i < 8; ++i) m2 = fmaxf(m2, wred[i]);
      atomicMaxF(&kmax[bh], m2);
    }
  }
}

// ---------------- stage_a: KV^T partial + z partial; coalesced kvT write ----------------
__global__ __launch_bounds__(512) void stage_a(
    const float* __restrict__ v, const float* __restrict__ kk,
    const u16* __restrict__ projbf, const float* __restrict__ kmax,
    u16* __restrict__ kvT, float* __restrict__ zp) {
  __shared__ __align__(16) u16 knl[128 * 72];     // 18,432
  __shared__ __align__(16) u16 Vt[64 * 136];      // 17,408  (V^T [d][t])
  __shared__ __align__(16) u16 strip[288 * 40];   // 23,040  (phi_k^T, then kv staging)
  __shared__ float dkl[128];
  const int tid = threadIdx.x, lane = tid & 63, wv = tid >> 6;
  const int lj = lane & 15, lg = lane >> 4;
  const int c = blockIdx.x & 31, bh = blockIdx.x >> 5;
  const int b = bh / Hn, h = bh % Hn;
  const int t0 = c * CH;
  const float kmx = kmax[bh];

#pragma unroll
  for (int l = 0; l < 2; ++l) {
    int idx = tid + l * 512;
    int t = idx >> 3, e8 = (idx & 7) * 8;
    const float* kr = &kk[(((size_t)b * Tn + t0 + t) * Hn + h) * 64 + e8];
    float4 u0 = *reinterpret_cast<const float4*>(kr);
    float4 u1 = *reinterpret_cast<const float4*>(kr + 4);
    float x0 = u0.x * DATA_NORM, x1 = u0.y * DATA_NORM;
    float x2 = u0.z * DATA_NORM, x3 = u0.w * DATA_NORM;
    float x4 = u1.x * DATA_NORM, x5 = u1.y * DATA_NORM;
    float x6 = u1.z * DATA_NORM, x7 = u1.w * DATA_NORM;
    float ss = x0*x0 + x1*x1 + x2*x2 + x3*x3 + x4*x4 + x5*x5 + x6*x6 + x7*x7;
    *reinterpret_cast<ushort4*>(&knl[t * 72 + e8]) =
        make_ushort4(f2bf(x0), f2bf(x1), f2bf(x2), f2bf(x3));
    *reinterpret_cast<ushort4*>(&knl[t * 72 + e8 + 4]) =
        make_ushort4(f2bf(x4), f2bf(x5), f2bf(x6), f2bf(x7));
    ss += __shfl_xor(ss, 1);
    ss += __shfl_xor(ss, 2);
    ss += __shfl_xor(ss, 4);
    if ((tid & 7) == 0) dkl[t] = 0.5f * ss;
  }
#pragma unroll
  for (int l = 0; l < 4; ++l) {   // V -> V^T LDS bf16
    int idx = tid + l * 512;
    int t = idx >> 4, d4 = (idx & 15) * 4;
    float4 vv = *reinterpret_cast<const float4*>(
        &v[(((size_t)b * Tn + t0 + t) * Hn + h) * 64 + d4]);
    Vt[(d4 + 0) * 136 + t] = f2bf(vv.x);
    Vt[(d4 + 1) * 136 + t] = f2bf(vv.y);
    Vt[(d4 + 2) * 136 + t] = f2bf(vv.z);
    Vt[(d4 + 3) * 136 + t] = f2bf(vv.w);
  }

  float zacc = 0.f;
  f32x4 kvacc[9];
#pragma unroll
  for (int i = 0; i < 9; ++i) kvacc[i] = (f32x4){0.f, 0.f, 0.f, 0.f};
  const int dtile = wv & 3, mg = wv >> 2;
  __syncthreads();

  for (int s = 0; s < 4; ++s) {
    if (s) __syncthreads();
#pragma unroll
    for (int i = 0; i < 5; ++i) {
      int idx = wv + 8 * i;
      if (idx < 36) {
        int mt = idx % 18, th = idx / 18;
        const u16* ar = &projbf[(mt * 16 + lj) * 64 + lg * 8];
        int trow = s * 32 + th * 16 + lj;
        const u16* br = &knl[trow * 72 + lg * 8];
        f32x4 z = {0.f, 0.f, 0.f, 0.f};
        z = mfma16(ldb(ar), ldb(br), z);
        z = mfma16(ldb(ar + 32), ldb(br + 32), z);
        float dgk = dkl[trow];
#pragma unroll
        for (int r = 0; r < 4; ++r) {
          int m = mt * 16 + lg * 4 + r;
          float val = (m < Mn) ? RATIO * (__expf(z[r] - dgk - kmx) + SM_EPS) : 0.f;
          strip[m * 40 + th * 16 + lj] = f2bf(val);
        }
      }
    }
    __syncthreads();
    if (tid < MP) {
      const u16* srow = &strip[tid * 40];
#pragma unroll
      for (int o = 0; o < 32; o += 8) {
        bf16x8 vv = ldb(srow + o);
#pragma unroll
        for (int e = 0; e < 8; ++e) zacc += bf2f((u16)vv[e]);
      }
    }
    {
      bf16x8 av = ldb(&Vt[(dtile * 16 + lj) * 136 + s * 32 + lg * 8]);
#pragma unroll
      for (int i = 0; i < 9; ++i) {
        int mt = mg * 9 + i;
        kvacc[i] = mfma16(av, ldb(&strip[(mt * 16 + lj) * 40 + lg * 8]), kvacc[i]);
      }
    }
  }
  if (tid < MP) zp[((size_t)bh * NC + c) * MP + tid] = zacc;

  // coalesced kvT write via strip staging (two 32-row halves)
  const size_t base2 = ((size_t)(bh * NC + c) * 64) * MP;
  for (int half = 0; half < 2; ++half) {
    __syncthreads();
    if ((dtile >> 1) == half) {
#pragma unroll
      for (int i = 0; i < 9; ++i) {
        int mt = mg * 9 + i;
#pragma unroll
        for (int r = 0; r < 4; ++r)
          strip[((dtile & 1) * 16 + lg * 4 + r) * 296 + mt * 16 + lj] =
              f2bf(kvacc[i][r]);
      }
    }
    __syncthreads();
#pragma unroll
    for (int l = 0; l < 3; ++l) {
      int idx = tid + l * 512;
      if (idx < 1152) {
        int row = idx / 36, c8 = (idx % 36) * 8;
        *reinterpret_cast<uint4*>(&kvT[base2 + (size_t)(half * 32 + row) * MP + c8]) =
            *reinterpret_cast<const uint4*>(&strip[row * 296 + c8]);
      }
    }
  }
}

// ---------------- scan_all (R18): fused scan_kv | scan_z ----------------
__global__ void scan_all(u16* __restrict__ kvT, float* __restrict__ zp) {
  int idx = blockIdx.x * 256 + threadIdx.x;
  const int NKV = BH * 64 * 36;
  if (idx < NKV) {
    int m8 = (idx % 36) * 8;
    int r = idx / 36;
    int d = r & 63, bh = r >> 6;
    u16* p = kvT + ((size_t)(bh * NC) * 64 + d) * MP + m8;
    const size_t cs = (size_t)64 * MP;
    float acc[8];
#pragma unroll
    for (int qq = 0; qq < 8; ++qq) acc[qq] = 0.f;
    for (int c = 0; c < NC; ++c) {
      uint4 raw = *reinterpret_cast<const uint4*>(p + c * cs);
      float in[8];
      unpack8v(raw, in);
      *reinterpret_cast<uint4*>(p + c * cs) = pack8(acc);
#pragma unroll
      for (int qq = 0; qq < 8; ++qq) acc[qq] += in[qq];
    }
  } else {
    int j = idx - NKV;
    if (j < BH * MP) {
      int m = j % MP, bh = j / MP;
      float* p = zp + (size_t)bh * NC * MP + m;
      float acc = 0.f;
      for (int c = 0; c < NC; ++c) {
        float x = p[(size_t)c * MP];
        p[(size_t)c * MP] = acc;
        acc += x;
      }
    }
  }
}

// ---------------- stage_c (R17): two 64-row halves, padded Albuf, k prefetch ----------------
// A = mask(QK^T) with phi_k recomputed per 64-row HALF; out = (A@V + Q@S_prev)/den
// Albuf padded triangular: tile-row tb pitch = 16(tb+1)+8 u16; base 128*tb*(tb+2).
// arena: halves = phik_h[64][296] + knh[64][72] (47.1KB); after = Vt[64][136].
__global__ __launch_bounds__(512, 4) void stage_c(
    const float* __restrict__ v, const float* __restrict__ kk,
    const u16* __restrict__ projbf, const float* __restrict__ kmax,
    const u16* __restrict__ phiq, const u16* __restrict__ kvT,
    const float* __restrict__ zp, float* __restrict__ out) {
  __shared__ __align__(16) u16 Albuf[10240];       // 20,480 (padded triangular)
  __shared__ __align__(16) u16 arena[23552];       // 47,104
  __shared__ float zl[MP];
  __shared__ float dklh[64];
  __shared__ float qzb[128];
  __shared__ float den[128];

  u16* phik_h = arena;              // [64][296]
  u16* knh    = arena + 64 * 296;   // [64][72]

  const int tid = threadIdx.x, lane = tid & 63, wv = tid >> 6;
  const int lj = lane & 15, lg = lane >> 4;
  const int c = blockIdx.x & 31, bh = blockIdx.x >> 5;
  const int b = bh / Hn, h = bh % Hn;
  const int t0 = c * CH;
  const float kmx = kmax[bh];
  const size_t qbase = ((size_t)bh * Tn + t0) * MP;
  const size_t kvbase = ((size_t)(bh * NC + c) * 64) * MP;

  // top prefetch: qa = phi_q A-fragments for row-tile wv (used by P2 AND P4)
  bf16x8 qa[9];
#pragma unroll
  for (int ks = 0; ks < 9; ++ks)
    qa[ks] = ldb(&phiq[qbase + (size_t)(wv * 16 + lj) * MP + ks * 32 + lg * 8]);
  // prologue: k for half 0 into regs (64 rows x 64 elems; 8 f32/thread)
  const int kt = tid >> 3, ke8 = (tid & 7) * 8;
  const float* kb0 = &kk[(((size_t)b * Tn + t0 + kt) * Hn + h) * 64 + ke8];
  float4 kp0 = *reinterpret_cast<const float4*>(kb0);
  float4 kp1 = *reinterpret_cast<const float4*>(kb0 + 4);
  __builtin_amdgcn_sched_barrier(0);

  if (tid < MP) zl[tid] = zp[((size_t)bh * NC + c) * MP + tid];

  for (int hh = 0; hh < 2; ++hh) {
    // write staged k -> knh bf16 + dklh (all 512 threads, 8 elems each)
    {
      float x0 = kp0.x * DATA_NORM, x1 = kp0.y * DATA_NORM;
      float x2 = kp0.z * DATA_NORM, x3 = kp0.w * DATA_NORM;
      float x4 = kp1.x * DATA_NORM, x5 = kp1.y * DATA_NORM;
      float x6 = kp1.z * DATA_NORM, x7 = kp1.w * DATA_NORM;
      float ss = x0*x0 + x1*x1 + x2*x2 + x3*x3 + x4*x4 + x5*x5 + x6*x6 + x7*x7;
      *reinterpret_cast<ushort4*>(&knh[kt * 72 + ke8]) =
          make_ushort4(f2bf(x0), f2bf(x1), f2bf(x2), f2bf(x3));
      *reinterpret_cast<ushort4*>(&knh[kt * 72 + ke8 + 4]) =
          make_ushort4(f2bf(x4), f2bf(x5), f2bf(x6), f2bf(x7));
      ss += __shfl_xor(ss, 1);
      ss += __shfl_xor(ss, 2);
      ss += __shfl_xor(ss, 4);
      if ((tid & 7) == 0) dklh[kt] = 0.5f * ss;
    }
    __syncthreads();   // knh ready (covers zl on first iteration)

    // issue next half's k load; flies under P1+P2
    if (hh == 0) {
      const float* kb1 = &kk[(((size_t)b * Tn + t0 + 64 + kt) * Hn + h) * 64 + ke8];
      kp0 = *reinterpret_cast<const float4*>(kb1);
      kp1 = *reinterpret_cast<const float4*>(kb1 + 4);
      __builtin_amdgcn_sched_barrier(0);
    }

    // P1: phi_k for half -> phik_h [64][296]; 72 units, exactly 9 per wave.
    for (int u = wv; u < 72; u += 8) {
      int t4 = u / 18, mt = u % 18;
      bf16x8 a0 = ldb(&knh[(t4 * 16 + lj) * 72 + lg * 8]);
      bf16x8 a1 = ldb(&knh[(t4 * 16 + lj) * 72 + 32 + lg * 8]);
      const u16* br = &projbf[(mt * 16 + lj) * 64 + lg * 8];
      f32x4 z = {0.f, 0.f, 0.f, 0.f};
      z = mfma16(a0, ldb(br), z);
      z = mfma16(a1, ldb(br + 32), z);
      int m = mt * 16 + lj;
      int tq = t4 * 16 + lg * 4;
#pragma unroll
      for (int r = 0; r < 4; ++r) {
        float val = (m < Mn)
            ? RATIO * (__expf(z[r] - dklh[tq + r] - kmx) + SM_EPS) : 0.f;
        phik_h[(tq + r) * 296 + m] = f2bf(val);
      }
    }
    __syncthreads();   // phik_h ready

    // P2: wave-owns-row; two tp-pairs per half (tp in {4hh..4hh+3}, tp<=wv)
    const int tpb = 4 * hh;
#pragma unroll
    for (int pr = 0; pr < 2; ++pr) {
      const int tp0 = tpb + 2 * pr, tp1 = tp0 + 1;
      const bool ha = (tp0 <= wv), hb = (tp1 <= wv);
      if (!ha) break;
      const int lr0 = (2 * pr) * 16, lr1 = (2 * pr + 1) * 16;   // local key rows
      f32x4 accA = {0.f, 0.f, 0.f, 0.f}, accB = {0.f, 0.f, 0.f, 0.f};
      __builtin_amdgcn_s_setprio(1);
#pragma unroll
      for (int ks = 0; ks < 9; ++ks) {
        int m0 = ks * 32;
        accA = mfma16(qa[ks], ldb(&phik_h[(lr0 + lj) * 296 + m0 + lg * 8]), accA);
        if (hb)
          accB = mfma16(qa[ks], ldb(&phik_h[(lr1 + lj) * 296 + m0 + lg * 8]), accB);
      }
      __builtin_amdgcn_s_setprio(0);
      const int rb = 128 * wv * (wv + 2);
      const int pitch = 16 * (wv + 1) + 8;
#pragma unroll
      for (int pick = 0; pick < 2; ++pick) {
        if (pick == 1 && !hb) break;
        int tp = pick ? tp1 : tp0;
        f32x4 a = pick ? accB : accA;
        if (tp == wv) {   // diagonal tile mask
#pragma unroll
          for (int r = 0; r < 4; ++r)
            if (lj > lg * 4 + r) a[r] = 0.f;
        }
#pragma unroll
        for (int r = 0; r < 4; ++r)
          Albuf[rb + (lg * 4 + r) * pitch + tp * 16 + lj] = f2bf(a[r]);
      }
    }
    __syncthreads();   // Albuf half-columns done; arena free for next half
  }

  // stage V^T into arena (phik_h/knh dead)
  u16* Vt = arena;
#pragma unroll
  for (int l = 0; l < 4; ++l) {
    int idx = tid + l * 512;
    int t = idx >> 4, d4 = (idx & 15) * 4;
    float4 vv = *reinterpret_cast<const float4*>(
        &v[(((size_t)b * Tn + t0 + t) * Hn + h) * 64 + d4]);
    Vt[(d4 + 0) * 136 + t] = f2bf(vv.x);
    Vt[(d4 + 1) * 136 + t] = f2bf(vv.y);
    Vt[(d4 + 2) * 136 + t] = f2bf(vv.z);
    Vt[(d4 + 3) * 136 + t] = f2bf(vv.w);
  }

  // prefetch P4 first kvT quad; pin issue before the barrier
  bf16x8 kbA[4], kbB[4];
#pragma unroll
  for (int dt = 0; dt < 4; ++dt)
    kbA[dt] = ldb(&kvT[kvbase + (size_t)(dt * 16 + lj) * MP + lg * 8]);
  __builtin_amdgcn_sched_barrier(0);
  __syncthreads();   // Vt ready

  // P3: O += A @ V (triangular k-step skip, padded A rows)
  f32x4 oacc[4];
#pragma unroll
  for (int dt = 0; dt < 4; ++dt) oacc[dt] = (f32x4){0.f, 0.f, 0.f, 0.f};
  const int ksteps = (wv >> 1) + 1;
  const int rowA = 128 * wv * (wv + 2) + lj * (16 * (wv + 1) + 8);
  const bf16x8 zf = {0, 0, 0, 0, 0, 0, 0, 0};
  __builtin_amdgcn_s_setprio(1);
  for (int ks = 0; ks < ksteps; ++ks) {
    bool dead = ((wv & 1) == 0) && (ks == ksteps - 1) && (lg >= 2);
    bf16x8 af = dead ? zf : ldb(&Albuf[rowA + ks * 32 + lg * 8]);
#pragma unroll
    for (int dt = 0; dt < 4; ++dt) {
      bf16x8 bf = ldb(&Vt[(dt * 16 + lj) * 136 + ks * 32 + lg * 8]);
      oacc[dt] = mfma16(af, bf, oacc[dt]);
    }
  }
  __builtin_amdgcn_s_setprio(0);

  // P4: O += phi_q @ S_prev; B double-buffered in regs; fused qz
  float qz = 0.f;
#pragma unroll
  for (int ks = 0; ks < 9; ++ks) {
    const bf16x8* cur = (ks & 1) ? kbB : kbA;
    bf16x8* nxt = (ks & 1) ? kbA : kbB;
    if (ks < 8) {
      int m1 = (ks + 1) * 32;
#pragma unroll
      for (int dt = 0; dt < 4; ++dt)
        nxt[dt] = ldb(&kvT[kvbase + (size_t)(dt * 16 + lj) * MP + m1 + lg * 8]);
    }
#pragma unroll
    for (int e = 0; e < 8; ++e)
      qz += bf2f((u16)qa[ks][e]) * zl[ks * 32 + lg * 8 + e];
#pragma unroll
    for (int dt = 0; dt < 4; ++dt)
      oacc[dt] = mfma16(qa[ks], cur[dt], oacc[dt]);
  }
  qz += __shfl_xor(qz, 16);
  qz += __shfl_xor(qz, 32);
  if (lane < 16) qzb[wv * 16 + lane] = qz;
  __syncthreads();

  // den from padded bf16 A rows + qz + eps
  if (tid < 128) {
    int tb2 = tid >> 4;
    int Lr = 16 * (tb2 + 1);
    const u16* arow = &Albuf[128 * tb2 * (tb2 + 2) + (tid & 15) * (Lr + 8)];
    float s = qzb[tid] + N_EPS;
    for (int cc = 0; cc < Lr; cc += 8) {
      bf16x8 vv = ldb(arow + cc);
#pragma unroll
      for (int e = 0; e < 8; ++e) s += bf2f((u16)vv[e]);
    }
    den[tid] = s;
  }
  __syncthreads();

#pragma unroll
  for (int dt = 0; dt < 4; ++dt) {
#pragma unroll
    for (int r = 0; r < 4; ++r) {
      int tl = wv * 16 + lg * 4 + r;
      float o = oacc[dt][r] / den[tl];
      out[(((size_t)b * Tn + t0 + tl) * Hn + h) * 64 + dt * 16 + lj] = o;
    }
  }
}

extern "C" void kernel_launch(void* const* d_in, const int* in_sizes, int n_in,
                              void* d_out, int out_size, void* d_ws, size_t ws_size,
                              hipStream_t stream) {
  const float* q = (const float*)d_in[0];
  const float* k = (const float*)d_in[1];
  const float* v = (const float*)d_in[2];
  const float* proj = (const float*)d_in[3];
  float* out = (float*)d_out;

  char* ws = (char*)d_ws;
  const size_t phiq_b = (size_t)BH * Tn * MP * 2;        // 113,246,208
  const size_t kvT_b  = (size_t)BH * NC * 64 * MP * 2;   //  56,623,104
  const size_t zp_b   = (size_t)BH * NC * MP * 4;        //   1,769,472
  const size_t pj_b   = (size_t)MP * 64 * 2;             //      36,864

  size_t off = 0;
  u16*   phiq  = (u16*)(ws + off);  off += phiq_b;
  u16*   kvT   = (u16*)(ws + off);  off += kvT_b;
  float* zp    = (float*)(ws + off); off += zp_b;
  u16*   projbf= (u16*)(ws + off);  off += pj_b;
  float* kmax  = (float*)(ws + off);

  prep<<<72, 256, 0, stream>>>(proj, projbf, kmax);
  featqk<<<2 * BH * 32, 512, 0, stream>>>(q, k, projbf, phiq, kmax);
  stage_a<<<BH * NC, 512, 0, stream>>>(v, k, projbf, kmax, kvT, zp);
  scan_all<<<(BH * 64 * 36 + BH * MP + 255) / 256, 256, 0, stream>>>(kvT, zp);
  stage_c<<<BH * NC, 512, 0, stream>>>(v, k, projbf, kmax, phiq, kvT, zp, out);
}